// Round 1
// baseline (1929.318 us; speedup 1.0000x reference)
//
#include <hip/hip_runtime.h>
#include <hip/hip_bf16.h>

#define N_NODES 100000
#define N_EDGES 3200000
#define N_GRAPHS 512
#define IN_DIM 29
#define HID 128
#define LAT 256

// ---------------- preprocessing: degree, CSR build ----------------

__global__ __launch_bounds__(256) void k_zero_int(int* p, int n) {
    int i = blockIdx.x * 256 + threadIdx.x;
    if (i < n) p[i] = 0;
}

__global__ __launch_bounds__(256) void k_hist(const int* __restrict__ dst, int* __restrict__ hist, int e) {
    int i = blockIdx.x * 256 + threadIdx.x;
    if (i < e) atomicAdd(&hist[dst[i]], 1);
}

__global__ __launch_bounds__(256) void k_dis(const int* __restrict__ hist, float* __restrict__ dis, int n) {
    int i = blockIdx.x * 256 + threadIdx.x;
    if (i < n) dis[i] = rsqrtf((float)hist[i] + 1.0f);
}

// scan1: per-block (1024 elems) inclusive scan into incl[], block total into partials[]
__global__ __launch_bounds__(256) void k_scan1(const int* __restrict__ hist, int* __restrict__ incl,
                                               int* __restrict__ partials, int n) {
    __shared__ int sh[256];
    int t = threadIdx.x;
    int base = blockIdx.x * 1024 + t * 4;
    int v0 = (base + 0 < n) ? hist[base + 0] : 0;
    int v1 = (base + 1 < n) ? hist[base + 1] : 0;
    int v2 = (base + 2 < n) ? hist[base + 2] : 0;
    int v3 = (base + 3 < n) ? hist[base + 3] : 0;
    int s = v0 + v1 + v2 + v3;
    sh[t] = s;
    __syncthreads();
    for (int off = 1; off < 256; off <<= 1) {
        int x = (t >= off) ? sh[t - off] : 0;
        __syncthreads();
        sh[t] += x;
        __syncthreads();
    }
    int excl = sh[t] - s;
    int run = excl;
    run += v0; if (base + 0 < n) incl[base + 0] = run;
    run += v1; if (base + 1 < n) incl[base + 1] = run;
    run += v2; if (base + 2 < n) incl[base + 2] = run;
    run += v3; if (base + 3 < n) incl[base + 3] = run;
    if (t == 0) partials[blockIdx.x] = sh[255];
}

// scan2: exclusive scan of partials (np <= 128), single block
__global__ __launch_bounds__(128) void k_scan2(int* partials, int np) {
    __shared__ int sh[128];
    int t = threadIdx.x;
    if (t < np) sh[t] = partials[t];
    __syncthreads();
    if (t == 0) {
        int run = 0;
        for (int i = 0; i < np; ++i) { int v = sh[i]; sh[i] = run; run += v; }
    }
    __syncthreads();
    if (t < np) partials[t] = sh[t];
}

// scan3: convert to global exclusive scan -> row_ptr and cursor
__global__ __launch_bounds__(256) void k_scan3(const int* __restrict__ hist, int* __restrict__ rp,
                                               const int* __restrict__ partials, int* __restrict__ cursor,
                                               int n, int total) {
    int i = blockIdx.x * 256 + threadIdx.x;
    if (i < n) {
        int excl = rp[i] - hist[i] + partials[i >> 10];
        rp[i] = excl;
        cursor[i] = excl;
    }
    if (i == n) rp[n] = total;
}

__global__ __launch_bounds__(256) void k_scatter(const int* __restrict__ src, const int* __restrict__ dst,
                                                 const float* __restrict__ dis, int* __restrict__ cursor,
                                                 int* __restrict__ col, float* __restrict__ ew, int e) {
    int i = blockIdx.x * 256 + threadIdx.x;
    if (i < e) {
        int s = src[i], d = dst[i];
        int pos = atomicAdd(&cursor[d], 1);
        col[pos] = s;
        ew[pos] = dis[s] * dis[d];
    }
}

// ---------------- dense GEMM: out[n][128] = in[n][K] @ W[K][128] ----------------
// W staged in LDS; block = 256 threads (2 halves x 128 channels), each half does
// 4 nodes at a time to amortize LDS reads 4x.

template <int K, int NPB>
__global__ __launch_bounds__(256) void k_gemm(const float* __restrict__ in, const float* __restrict__ W,
                                              float* __restrict__ out, int n) {
    __shared__ float w[K * 128];
    for (int i = threadIdx.x; i < K * 128; i += 256) w[i] = W[i];
    __syncthreads();
    const int c = threadIdx.x & 127;
    const int half = threadIdx.x >> 7;
    const int base = blockIdx.x * NPB + half * (NPB / 2);
    for (int nb = 0; nb < NPB / 2; nb += 4) {
        int i0 = base + nb;
        if (i0 >= n) break;
        int i1 = i0 + 1 < n ? i0 + 1 : n - 1;
        int i2 = i0 + 2 < n ? i0 + 2 : n - 1;
        int i3 = i0 + 3 < n ? i0 + 3 : n - 1;
        const float* r0 = in + (size_t)i0 * K;
        const float* r1 = in + (size_t)i1 * K;
        const float* r2 = in + (size_t)i2 * K;
        const float* r3 = in + (size_t)i3 * K;
        float a0 = 0.f, a1 = 0.f, a2 = 0.f, a3 = 0.f;
        if constexpr ((K & 3) == 0) {
            for (int k = 0; k < K; k += 4) {
                float4 h0 = *(const float4*)(r0 + k);
                float4 h1 = *(const float4*)(r1 + k);
                float4 h2 = *(const float4*)(r2 + k);
                float4 h3 = *(const float4*)(r3 + k);
                float w0 = w[(k + 0) * 128 + c];
                float w1 = w[(k + 1) * 128 + c];
                float w2 = w[(k + 2) * 128 + c];
                float w3 = w[(k + 3) * 128 + c];
                a0 += h0.x * w0 + h0.y * w1 + h0.z * w2 + h0.w * w3;
                a1 += h1.x * w0 + h1.y * w1 + h1.z * w2 + h1.w * w3;
                a2 += h2.x * w0 + h2.y * w1 + h2.z * w2 + h2.w * w3;
                a3 += h3.x * w0 + h3.y * w1 + h3.z * w2 + h3.w * w3;
            }
        } else {
            for (int k = 0; k < K; ++k) {
                float w0 = w[k * 128 + c];
                a0 += r0[k] * w0;
                a1 += r1[k] * w0;
                a2 += r2[k] * w0;
                a3 += r3[k] * w0;
            }
        }
        out[(size_t)i0 * 128 + c] = a0;
        if (i0 + 1 < n) out[(size_t)(i0 + 1) * 128 + c] = a1;
        if (i0 + 2 < n) out[(size_t)(i0 + 2) * 128 + c] = a2;
        if (i0 + 3 < n) out[(size_t)(i0 + 3) * 128 + c] = a3;
    }
}

// ---------------- aggregation: one wave per node, lane = 2 channels ----------------
// out[i][:] = relu( sum_{j in row i} ew[j]*hw[col[j]][:] + dis[i]^2*hw[i][:] + b[:] )

__global__ __launch_bounds__(256) void k_agg(const float* __restrict__ hw, const int* __restrict__ rp,
                                             const int* __restrict__ col, const float* __restrict__ ew,
                                             const float* __restrict__ dis, const float* __restrict__ bias,
                                             float* __restrict__ out, int n) {
    int node = (int)((blockIdx.x * 256 + threadIdx.x) >> 6);
    if (node >= n) return;
    int lane = threadIdx.x & 63;
    int c2 = lane << 1;
    int s = rp[node], e = rp[node + 1];
    float ax0 = 0.f, ay0 = 0.f, ax1 = 0.f, ay1 = 0.f;
    int j = s;
    for (; j + 1 < e; j += 2) {
        int nb0 = col[j], nb1 = col[j + 1];
        float w0 = ew[j], w1 = ew[j + 1];
        float2 v0 = *(const float2*)(hw + ((size_t)nb0 << 7) + c2);
        float2 v1 = *(const float2*)(hw + ((size_t)nb1 << 7) + c2);
        ax0 += v0.x * w0; ay0 += v0.y * w0;
        ax1 += v1.x * w1; ay1 += v1.y * w1;
    }
    if (j < e) {
        int nb = col[j];
        float w0 = ew[j];
        float2 v = *(const float2*)(hw + ((size_t)nb << 7) + c2);
        ax0 += v.x * w0; ay0 += v.y * w0;
    }
    float d = dis[node];
    float sw = d * d;
    float2 hv = *(const float2*)(hw + ((size_t)node << 7) + c2);
    float rx = ax0 + ax1 + hv.x * sw + bias[c2];
    float ry = ay0 + ay1 + hv.y * sw + bias[c2 + 1];
    rx = fmaxf(rx, 0.f);
    ry = fmaxf(ry, 0.f);
    float2 res; res.x = rx; res.y = ry;
    *(float2*)(out + ((size_t)node << 7) + c2) = res;
}

// ---------------- fused mean-pool + heads ----------------
// batch is sorted; block g binary-searches [start,end), mean-pools h, then
// mu = pooled@Wmu+bmu, logvar = pooled@Wlv+blv.

__global__ __launch_bounds__(256) void k_pool_head(const float* __restrict__ h, const int* __restrict__ batch,
                                                   const float* __restrict__ Wmu, const float* __restrict__ bmu,
                                                   const float* __restrict__ Wlv, const float* __restrict__ blv,
                                                   float* __restrict__ out, int n) {
    int g = blockIdx.x;
    int t = threadIdx.x;
    int lo = 0, hi = n;
    while (lo < hi) { int m = (lo + hi) >> 1; if (batch[m] < g) lo = m + 1; else hi = m; }
    int start = lo;
    hi = n;
    while (lo < hi) { int m = (lo + hi) >> 1; if (batch[m] < g + 1) lo = m + 1; else hi = m; }
    int end = lo;

    __shared__ float sh[256];
    __shared__ float pooled[128];
    int c = t & 127, half = t >> 7;
    float acc = 0.f;
    for (int i = start + half; i < end; i += 2) acc += h[(size_t)i * 128 + c];
    sh[t] = acc;
    __syncthreads();
    if (t < 128) {
        float cnt = (float)(end - start);
        float inv = 1.0f / fmaxf(cnt, 1.0f);
        pooled[t] = (sh[t] + sh[t + 128]) * inv;
    }
    __syncthreads();
    float amu = bmu[t], alv = blv[t];
    for (int k = 0; k < 128; k += 4) {
        float p0 = pooled[k], p1 = pooled[k + 1], p2 = pooled[k + 2], p3 = pooled[k + 3];
        amu += p0 * Wmu[(k + 0) * 256 + t] + p1 * Wmu[(k + 1) * 256 + t]
             + p2 * Wmu[(k + 2) * 256 + t] + p3 * Wmu[(k + 3) * 256 + t];
        alv += p0 * Wlv[(k + 0) * 256 + t] + p1 * Wlv[(k + 1) * 256 + t]
             + p2 * Wlv[(k + 2) * 256 + t] + p3 * Wlv[(k + 3) * 256 + t];
    }
    out[(size_t)g * 256 + t] = amu;
    out[(size_t)N_GRAPHS * 256 + (size_t)g * 256 + t] = alv;
}

// ---------------- launch ----------------

extern "C" void kernel_launch(void* const* d_in, const int* in_sizes, int n_in,
                              void* d_out, int out_size, void* d_ws, size_t ws_size,
                              hipStream_t stream) {
    const float* x    = (const float*)d_in[0];
    const int*   eidx = (const int*)d_in[1];   // [2, E] flat: src then dst
    const int*   batch= (const int*)d_in[2];
    const float* W1   = (const float*)d_in[3];
    const float* b1   = (const float*)d_in[4];
    const float* W2   = (const float*)d_in[5];
    const float* b2   = (const float*)d_in[6];
    const float* W3   = (const float*)d_in[7];
    const float* b3   = (const float*)d_in[8];
    const float* Wmu  = (const float*)d_in[9];
    const float* bmu  = (const float*)d_in[10];
    const float* Wlv  = (const float*)d_in[11];
    const float* blv  = (const float*)d_in[12];
    float* out = (float*)d_out;

    const int N = N_NODES, E = N_EDGES;
    const int* srcp = eidx;
    const int* dstp = eidx + E;

    // workspace layout
    float* A       = (float*)d_ws;                 // N*128  (hw buffer)
    float* B       = A + (size_t)N * 128;          // N*128  (h buffer)
    float* dis     = B + (size_t)N * 128;          // N
    int*   hist    = (int*)(dis + N);              // N
    int*   row_ptr = hist + N;                     // N+1
    int*   cursor  = row_ptr + (N + 1);            // N
    int*   partials= cursor + N;                   // 128
    int*   col     = partials + 128;               // E
    float* ew      = (float*)(col + E);            // E

    const int gN   = (N + 255) / 256;          // covers N (and N+1: 391*256 > 100001)
    const int gE   = (E + 255) / 256;
    const int nScanBlocks = (N + 1023) / 1024; // 98

    // CSR build
    k_zero_int<<<gN, 256, 0, stream>>>(hist, N);
    k_hist<<<gE, 256, 0, stream>>>(dstp, hist, E);
    k_dis<<<gN, 256, 0, stream>>>(hist, dis, N);
    k_scan1<<<nScanBlocks, 256, 0, stream>>>(hist, row_ptr, partials, N);
    k_scan2<<<1, 128, 0, stream>>>(partials, nScanBlocks);
    k_scan3<<<gN, 256, 0, stream>>>(hist, row_ptr, partials, cursor, N, E);
    k_scatter<<<gE, 256, 0, stream>>>(srcp, dstp, dis, cursor, col, ew, E);

    const int NPB = 16;
    const int gGemm = (N + NPB - 1) / NPB;
    const int gAgg  = (N + 3) / 4;  // 4 nodes (waves) per 256-thread block

    // layer 1: A = x@W1 ; B = relu(agg(A)+self+b1)
    k_gemm<IN_DIM, NPB><<<gGemm, 256, 0, stream>>>(x, W1, A, N);
    k_agg<<<gAgg, 256, 0, stream>>>(A, row_ptr, col, ew, dis, b1, B, N);
    // layer 2
    k_gemm<HID, NPB><<<gGemm, 256, 0, stream>>>(B, W2, A, N);
    k_agg<<<gAgg, 256, 0, stream>>>(A, row_ptr, col, ew, dis, b2, B, N);
    // layer 3
    k_gemm<HID, NPB><<<gGemm, 256, 0, stream>>>(B, W3, A, N);
    k_agg<<<gAgg, 256, 0, stream>>>(A, row_ptr, col, ew, dis, b3, B, N);
    // pool + heads
    k_pool_head<<<N_GRAPHS, 256, 0, stream>>>(B, batch, Wmu, bmu, Wlv, blv, out, N);
}

// Round 2
// 1551.642 us; speedup vs baseline: 1.2434x; 1.2434x over previous
//
#include <hip/hip_runtime.h>
#include <hip/hip_bf16.h>

#define N_NODES 100000
#define N_EDGES 3200000
#define N_GRAPHS 512
#define IN_DIM 29
#define HID 128
#define LAT 256

// ---------------- preprocessing: degree, CSR build ----------------

__global__ __launch_bounds__(256) void k_zero_int(int* p, int n) {
    int i = blockIdx.x * 256 + threadIdx.x;
    if (i < n) p[i] = 0;
}

__global__ __launch_bounds__(256) void k_hist(const int* __restrict__ dst, int* __restrict__ hist, int e) {
    int i = blockIdx.x * 256 + threadIdx.x;
    if (i < e) atomicAdd(&hist[dst[i]], 1);
}

__global__ __launch_bounds__(256) void k_dis(const int* __restrict__ hist, float* __restrict__ dis, int n) {
    int i = blockIdx.x * 256 + threadIdx.x;
    if (i < n) dis[i] = rsqrtf((float)hist[i] + 1.0f);
}

// scan1: per-block (1024 elems) inclusive scan into incl[], block total into partials[]
__global__ __launch_bounds__(256) void k_scan1(const int* __restrict__ hist, int* __restrict__ incl,
                                               int* __restrict__ partials, int n) {
    __shared__ int sh[256];
    int t = threadIdx.x;
    int base = blockIdx.x * 1024 + t * 4;
    int v0 = (base + 0 < n) ? hist[base + 0] : 0;
    int v1 = (base + 1 < n) ? hist[base + 1] : 0;
    int v2 = (base + 2 < n) ? hist[base + 2] : 0;
    int v3 = (base + 3 < n) ? hist[base + 3] : 0;
    int s = v0 + v1 + v2 + v3;
    sh[t] = s;
    __syncthreads();
    for (int off = 1; off < 256; off <<= 1) {
        int x = (t >= off) ? sh[t - off] : 0;
        __syncthreads();
        sh[t] += x;
        __syncthreads();
    }
    int excl = sh[t] - s;
    int run = excl;
    run += v0; if (base + 0 < n) incl[base + 0] = run;
    run += v1; if (base + 1 < n) incl[base + 1] = run;
    run += v2; if (base + 2 < n) incl[base + 2] = run;
    run += v3; if (base + 3 < n) incl[base + 3] = run;
    if (t == 0) partials[blockIdx.x] = sh[255];
}

// scan2: exclusive scan of partials (np <= 128), single block
__global__ __launch_bounds__(128) void k_scan2(int* partials, int np) {
    __shared__ int sh[128];
    int t = threadIdx.x;
    if (t < np) sh[t] = partials[t];
    __syncthreads();
    if (t == 0) {
        int run = 0;
        for (int i = 0; i < np; ++i) { int v = sh[i]; sh[i] = run; run += v; }
    }
    __syncthreads();
    if (t < np) partials[t] = sh[t];
}

// scan3: convert to global exclusive scan -> row_ptr and cursor
__global__ __launch_bounds__(256) void k_scan3(const int* __restrict__ hist, int* __restrict__ rp,
                                               const int* __restrict__ partials, int* __restrict__ cursor,
                                               int n, int total) {
    int i = blockIdx.x * 256 + threadIdx.x;
    if (i < n) {
        int excl = rp[i] - hist[i] + partials[i >> 10];
        rp[i] = excl;
        cursor[i] = excl;
    }
    if (i == n) rp[n] = total;
}

__global__ __launch_bounds__(256) void k_scatter(const int* __restrict__ src, const int* __restrict__ dst,
                                                 const float* __restrict__ dis, int* __restrict__ cursor,
                                                 int2* __restrict__ cw, int e) {
    int i = blockIdx.x * 256 + threadIdx.x;
    if (i < e) {
        int s = src[i], d = dst[i];
        int pos = atomicAdd(&cursor[d], 1);
        int2 p; p.x = s; p.y = __float_as_int(dis[s] * dis[d]);
        cw[pos] = p;
    }
}

// ---------------- dense GEMM: out[n][128] = in[n][K] @ W[K][128] ----------------
// W staged in LDS. Block = 1024 threads = 8 groups x 128 channels; each group
// computes 4 nodes; node rows loaded via wave-broadcast float4 (L1-served).
// __launch_bounds__(1024,8) caps VGPR<=64 so 2 blocks/CU (128KB LDS) = 100% occ.

template <int K>
__global__ __launch_bounds__(1024, 8) void k_gemm(const float* __restrict__ in, const float* __restrict__ W,
                                                  float* __restrict__ out, int n) {
    __shared__ float w[K * 128];
    for (int i = threadIdx.x; i < K * 128; i += 1024) w[i] = W[i];
    __syncthreads();
    const int c = threadIdx.x & 127;
    const int grp = threadIdx.x >> 7;                // 0..7
    const int i0 = (blockIdx.x * 8 + grp) * 4;
    if (i0 >= n) return;
    const int i1 = (i0 + 1 < n) ? i0 + 1 : n - 1;
    const int i2 = (i0 + 2 < n) ? i0 + 2 : n - 1;
    const int i3 = (i0 + 3 < n) ? i0 + 3 : n - 1;
    const float* r0 = in + (size_t)i0 * K;
    const float* r1 = in + (size_t)i1 * K;
    const float* r2 = in + (size_t)i2 * K;
    const float* r3 = in + (size_t)i3 * K;
    float a0 = 0.f, a1 = 0.f, a2 = 0.f, a3 = 0.f;
    if constexpr ((K & 3) == 0) {
        #pragma unroll 1
        for (int k = 0; k < K; k += 4) {
            float4 h0 = *(const float4*)(r0 + k);
            float4 h1 = *(const float4*)(r1 + k);
            float4 h2 = *(const float4*)(r2 + k);
            float4 h3 = *(const float4*)(r3 + k);
            float w0 = w[(k + 0) * 128 + c];
            float w1 = w[(k + 1) * 128 + c];
            float w2 = w[(k + 2) * 128 + c];
            float w3 = w[(k + 3) * 128 + c];
            a0 += h0.x * w0 + h0.y * w1 + h0.z * w2 + h0.w * w3;
            a1 += h1.x * w0 + h1.y * w1 + h1.z * w2 + h1.w * w3;
            a2 += h2.x * w0 + h2.y * w1 + h2.z * w2 + h2.w * w3;
            a3 += h3.x * w0 + h3.y * w1 + h3.z * w2 + h3.w * w3;
        }
    } else {
        #pragma unroll 1
        for (int k = 0; k < K; ++k) {
            float w0 = w[k * 128 + c];
            a0 += r0[k] * w0;
            a1 += r1[k] * w0;
            a2 += r2[k] * w0;
            a3 += r3[k] * w0;
        }
    }
    out[(size_t)i0 * 128 + c] = a0;
    if (i0 + 1 < n) out[(size_t)(i0 + 1) * 128 + c] = a1;
    if (i0 + 2 < n) out[(size_t)(i0 + 2) * 128 + c] = a2;
    if (i0 + 3 < n) out[(size_t)(i0 + 3) * 128 + c] = a3;
}

// ---------------- aggregation: 32 lanes per node, lane = 4 channels ----------------
// out[i][:] = relu( sum_{j in row i} ew[j]*hw[col[j]][:] + dis[i]^2*hw[i][:] + b[:] )
// 4 edges in flight (b128 gathers), packed (col,ew) metadata.

__global__ __launch_bounds__(256, 8) void k_agg(const float* __restrict__ hw, const int* __restrict__ rp,
                                                const int2* __restrict__ cw, const float* __restrict__ dis,
                                                const float* __restrict__ bias, float* __restrict__ out, int n) {
    int node = (int)((blockIdx.x * 256 + threadIdx.x) >> 5);
    if (node >= n) return;
    int lane = threadIdx.x & 31;
    int c4 = lane << 2;
    int s = rp[node], e = rp[node + 1];
    float ax = 0.f, ay = 0.f, az = 0.f, aw = 0.f;
    float bx = 0.f, by = 0.f, bz = 0.f, bw = 0.f;
    int j = s;
    for (; j + 3 < e; j += 4) {
        int2 p0 = cw[j], p1 = cw[j + 1], p2 = cw[j + 2], p3 = cw[j + 3];
        float4 v0 = *(const float4*)(hw + ((size_t)p0.x << 7) + c4);
        float4 v1 = *(const float4*)(hw + ((size_t)p1.x << 7) + c4);
        float4 v2 = *(const float4*)(hw + ((size_t)p2.x << 7) + c4);
        float4 v3 = *(const float4*)(hw + ((size_t)p3.x << 7) + c4);
        float w0 = __int_as_float(p0.y), w1 = __int_as_float(p1.y);
        float w2 = __int_as_float(p2.y), w3 = __int_as_float(p3.y);
        ax += v0.x * w0; ay += v0.y * w0; az += v0.z * w0; aw += v0.w * w0;
        bx += v1.x * w1; by += v1.y * w1; bz += v1.z * w1; bw += v1.w * w1;
        ax += v2.x * w2; ay += v2.y * w2; az += v2.z * w2; aw += v2.w * w2;
        bx += v3.x * w3; by += v3.y * w3; bz += v3.z * w3; bw += v3.w * w3;
    }
    for (; j < e; ++j) {
        int2 p = cw[j];
        float wj = __int_as_float(p.y);
        float4 v = *(const float4*)(hw + ((size_t)p.x << 7) + c4);
        ax += v.x * wj; ay += v.y * wj; az += v.z * wj; aw += v.w * wj;
    }
    float d = dis[node];
    float sw = d * d;
    float4 hv = *(const float4*)(hw + ((size_t)node << 7) + c4);
    float4 bv = *(const float4*)(bias + c4);
    float4 r;
    r.x = fmaxf(ax + bx + hv.x * sw + bv.x, 0.f);
    r.y = fmaxf(ay + by + hv.y * sw + bv.y, 0.f);
    r.z = fmaxf(az + bz + hv.z * sw + bv.z, 0.f);
    r.w = fmaxf(aw + bw + hv.w * sw + bv.w, 0.f);
    *(float4*)(out + ((size_t)node << 7) + c4) = r;
}

// ---------------- fused mean-pool + heads ----------------

__global__ __launch_bounds__(256) void k_pool_head(const float* __restrict__ h, const int* __restrict__ batch,
                                                   const float* __restrict__ Wmu, const float* __restrict__ bmu,
                                                   const float* __restrict__ Wlv, const float* __restrict__ blv,
                                                   float* __restrict__ out, int n) {
    int g = blockIdx.x;
    int t = threadIdx.x;
    int lo = 0, hi = n;
    while (lo < hi) { int m = (lo + hi) >> 1; if (batch[m] < g) lo = m + 1; else hi = m; }
    int start = lo;
    hi = n;
    while (lo < hi) { int m = (lo + hi) >> 1; if (batch[m] < g + 1) lo = m + 1; else hi = m; }
    int end = lo;

    __shared__ float sh[256];
    __shared__ float pooled[128];
    int c = t & 127, half = t >> 7;
    float acc = 0.f;
    for (int i = start + half; i < end; i += 2) acc += h[(size_t)i * 128 + c];
    sh[t] = acc;
    __syncthreads();
    if (t < 128) {
        float cnt = (float)(end - start);
        float inv = 1.0f / fmaxf(cnt, 1.0f);
        pooled[t] = (sh[t] + sh[t + 128]) * inv;
    }
    __syncthreads();
    float amu = bmu[t], alv = blv[t];
    for (int k = 0; k < 128; k += 4) {
        float p0 = pooled[k], p1 = pooled[k + 1], p2 = pooled[k + 2], p3 = pooled[k + 3];
        amu += p0 * Wmu[(k + 0) * 256 + t] + p1 * Wmu[(k + 1) * 256 + t]
             + p2 * Wmu[(k + 2) * 256 + t] + p3 * Wmu[(k + 3) * 256 + t];
        alv += p0 * Wlv[(k + 0) * 256 + t] + p1 * Wlv[(k + 1) * 256 + t]
             + p2 * Wlv[(k + 2) * 256 + t] + p3 * Wlv[(k + 3) * 256 + t];
    }
    out[(size_t)g * 256 + t] = amu;
    out[(size_t)N_GRAPHS * 256 + (size_t)g * 256 + t] = alv;
}

// ---------------- launch ----------------

extern "C" void kernel_launch(void* const* d_in, const int* in_sizes, int n_in,
                              void* d_out, int out_size, void* d_ws, size_t ws_size,
                              hipStream_t stream) {
    const float* x    = (const float*)d_in[0];
    const int*   eidx = (const int*)d_in[1];   // [2, E] flat: src then dst
    const int*   batch= (const int*)d_in[2];
    const float* W1   = (const float*)d_in[3];
    const float* b1   = (const float*)d_in[4];
    const float* W2   = (const float*)d_in[5];
    const float* b2   = (const float*)d_in[6];
    const float* W3   = (const float*)d_in[7];
    const float* b3   = (const float*)d_in[8];
    const float* Wmu  = (const float*)d_in[9];
    const float* bmu  = (const float*)d_in[10];
    const float* Wlv  = (const float*)d_in[11];
    const float* blv  = (const float*)d_in[12];
    float* out = (float*)d_out;

    const int N = N_NODES, E = N_EDGES;
    const int* srcp = eidx;
    const int* dstp = eidx + E;

    // workspace layout (int2 cw needs 8B alignment: counts before it are even)
    float* A       = (float*)d_ws;                 // N*128
    float* B       = A + (size_t)N * 128;          // N*128
    float* dis     = B + (size_t)N * 128;          // N
    int*   hist    = (int*)(dis + N);              // N
    int*   row_ptr = hist + N;                     // N+2 (padded even)
    int*   cursor  = row_ptr + (N + 2);            // N
    int*   partials= cursor + N;                   // 128
    int2*  cw      = (int2*)(partials + 128);      // E

    const int gN   = (N + 255) / 256;   // 391 blocks: covers i==N for k_scan3
    const int gE   = (E + 255) / 256;
    const int nScanBlocks = (N + 1023) / 1024;

    // CSR build
    k_zero_int<<<gN, 256, 0, stream>>>(hist, N);
    k_hist<<<gE, 256, 0, stream>>>(dstp, hist, E);
    k_dis<<<gN, 256, 0, stream>>>(hist, dis, N);
    k_scan1<<<nScanBlocks, 256, 0, stream>>>(hist, row_ptr, partials, N);
    k_scan2<<<1, 128, 0, stream>>>(partials, nScanBlocks);
    k_scan3<<<gN, 256, 0, stream>>>(hist, row_ptr, partials, cursor, N, E);
    k_scatter<<<gE, 256, 0, stream>>>(srcp, dstp, dis, cursor, cw, E);

    const int gGemm = (N + 31) / 32;   // 32 nodes per 1024-thread block
    const int gAgg  = (N + 7) / 8;     // 8 nodes per 256-thread block

    // layer 1: A = x@W1 ; B = relu(agg(A)+self+b1)
    k_gemm<IN_DIM><<<gGemm, 1024, 0, stream>>>(x, W1, A, N);
    k_agg<<<gAgg, 256, 0, stream>>>(A, row_ptr, cw, dis, b1, B, N);
    // layer 2
    k_gemm<HID><<<gGemm, 1024, 0, stream>>>(B, W2, A, N);
    k_agg<<<gAgg, 256, 0, stream>>>(A, row_ptr, cw, dis, b2, B, N);
    // layer 3
    k_gemm<HID><<<gGemm, 1024, 0, stream>>>(B, W3, A, N);
    k_agg<<<gAgg, 256, 0, stream>>>(A, row_ptr, cw, dis, b3, B, N);
    // pool + heads
    k_pool_head<<<N_GRAPHS, 256, 0, stream>>>(B, batch, Wmu, bmu, Wlv, blv, out, N);
}

// Round 3
// 1221.182 us; speedup vs baseline: 1.5799x; 1.2706x over previous
//
#include <hip/hip_runtime.h>
#include <hip/hip_bf16.h>

#define N_NODES 100000
#define N_EDGES 3200000
#define N_GRAPHS 512
#define IN_DIM 29
#define HID 128
#define LAT 256

typedef unsigned int uint;
typedef unsigned short ushort;

// round-to-nearest-even fp32 -> bf16 (finite inputs)
__device__ __forceinline__ ushort f2bf(float f) {
    uint u = __float_as_uint(f);
    return (ushort)((u + 0x7FFFu + ((u >> 16) & 1u)) >> 16);
}
__device__ __forceinline__ float bf_lo(uint p) { return __uint_as_float(p << 16); }
__device__ __forceinline__ float bf_hi(uint p) { return __uint_as_float(p & 0xFFFF0000u); }

// ---------------- preprocessing: degree, CSR build ----------------

__global__ __launch_bounds__(256) void k_zero_int(int* p, int n) {
    int i = blockIdx.x * 256 + threadIdx.x;
    if (i < n) p[i] = 0;
}

__global__ __launch_bounds__(256) void k_hist(const int* __restrict__ dst, int* __restrict__ hist, int e) {
    int i = blockIdx.x * 256 + threadIdx.x;
    if (i < e) atomicAdd(&hist[dst[i]], 1);
}

__global__ __launch_bounds__(256) void k_dis(const int* __restrict__ hist, float* __restrict__ dis, int n) {
    int i = blockIdx.x * 256 + threadIdx.x;
    if (i < n) dis[i] = rsqrtf((float)hist[i] + 1.0f);
}

__global__ __launch_bounds__(256) void k_scan1(const int* __restrict__ hist, int* __restrict__ incl,
                                               int* __restrict__ partials, int n) {
    __shared__ int sh[256];
    int t = threadIdx.x;
    int base = blockIdx.x * 1024 + t * 4;
    int v0 = (base + 0 < n) ? hist[base + 0] : 0;
    int v1 = (base + 1 < n) ? hist[base + 1] : 0;
    int v2 = (base + 2 < n) ? hist[base + 2] : 0;
    int v3 = (base + 3 < n) ? hist[base + 3] : 0;
    int s = v0 + v1 + v2 + v3;
    sh[t] = s;
    __syncthreads();
    for (int off = 1; off < 256; off <<= 1) {
        int x = (t >= off) ? sh[t - off] : 0;
        __syncthreads();
        sh[t] += x;
        __syncthreads();
    }
    int excl = sh[t] - s;
    int run = excl;
    run += v0; if (base + 0 < n) incl[base + 0] = run;
    run += v1; if (base + 1 < n) incl[base + 1] = run;
    run += v2; if (base + 2 < n) incl[base + 2] = run;
    run += v3; if (base + 3 < n) incl[base + 3] = run;
    if (t == 0) partials[blockIdx.x] = sh[255];
}

__global__ __launch_bounds__(128) void k_scan2(int* partials, int np) {
    __shared__ int sh[128];
    int t = threadIdx.x;
    if (t < np) sh[t] = partials[t];
    __syncthreads();
    if (t == 0) {
        int run = 0;
        for (int i = 0; i < np; ++i) { int v = sh[i]; sh[i] = run; run += v; }
    }
    __syncthreads();
    if (t < np) partials[t] = sh[t];
}

__global__ __launch_bounds__(256) void k_scan3(const int* __restrict__ hist, int* __restrict__ rp,
                                               const int* __restrict__ partials, int* __restrict__ cursor,
                                               int n, int total) {
    int i = blockIdx.x * 256 + threadIdx.x;
    if (i < n) {
        int excl = rp[i] - hist[i] + partials[i >> 10];
        rp[i] = excl;
        cursor[i] = excl;
    }
    if (i == n) rp[n] = total;
}

__global__ __launch_bounds__(256) void k_scatter(const int* __restrict__ src, const int* __restrict__ dst,
                                                 const float* __restrict__ dis, int* __restrict__ cursor,
                                                 int2* __restrict__ cw, int e) {
    int i = blockIdx.x * 256 + threadIdx.x;
    if (i < e) {
        int s = src[i], d = dst[i];
        int pos = atomicAdd(&cursor[d], 1);
        int2 p; p.x = s; p.y = __float_as_int(dis[s] * dis[d]);
        cw[pos] = p;
    }
}

// ---------------- dense GEMM: out_bf16[n][128] = in_f32[n][K] @ W[K][128] ----------------
// W staged in LDS. Block = 1024 threads = 8 groups x 128 channels; each group
// computes 4 nodes. __launch_bounds__(1024,8) caps VGPR<=64 -> 2 blocks/CU.

template <int K>
__global__ __launch_bounds__(1024, 8) void k_gemm(const float* __restrict__ in, const float* __restrict__ W,
                                                  ushort* __restrict__ out, int n) {
    __shared__ float w[K * 128];
    for (int i = threadIdx.x; i < K * 128; i += 1024) w[i] = W[i];
    __syncthreads();
    const int c = threadIdx.x & 127;
    const int grp = threadIdx.x >> 7;
    const int i0 = (blockIdx.x * 8 + grp) * 4;
    if (i0 >= n) return;
    const int i1 = (i0 + 1 < n) ? i0 + 1 : n - 1;
    const int i2 = (i0 + 2 < n) ? i0 + 2 : n - 1;
    const int i3 = (i0 + 3 < n) ? i0 + 3 : n - 1;
    const float* r0 = in + (size_t)i0 * K;
    const float* r1 = in + (size_t)i1 * K;
    const float* r2 = in + (size_t)i2 * K;
    const float* r3 = in + (size_t)i3 * K;
    float a0 = 0.f, a1 = 0.f, a2 = 0.f, a3 = 0.f;
    if constexpr ((K & 3) == 0) {
        #pragma unroll 1
        for (int k = 0; k < K; k += 4) {
            float4 h0 = *(const float4*)(r0 + k);
            float4 h1 = *(const float4*)(r1 + k);
            float4 h2 = *(const float4*)(r2 + k);
            float4 h3 = *(const float4*)(r3 + k);
            float w0 = w[(k + 0) * 128 + c];
            float w1 = w[(k + 1) * 128 + c];
            float w2 = w[(k + 2) * 128 + c];
            float w3 = w[(k + 3) * 128 + c];
            a0 += h0.x * w0 + h0.y * w1 + h0.z * w2 + h0.w * w3;
            a1 += h1.x * w0 + h1.y * w1 + h1.z * w2 + h1.w * w3;
            a2 += h2.x * w0 + h2.y * w1 + h2.z * w2 + h2.w * w3;
            a3 += h3.x * w0 + h3.y * w1 + h3.z * w2 + h3.w * w3;
        }
    } else {
        #pragma unroll 1
        for (int k = 0; k < K; ++k) {
            float w0 = w[k * 128 + c];
            a0 += r0[k] * w0;
            a1 += r1[k] * w0;
            a2 += r2[k] * w0;
            a3 += r3[k] * w0;
        }
    }
    out[(size_t)i0 * 128 + c] = f2bf(a0);
    if (i0 + 1 < n) out[(size_t)(i0 + 1) * 128 + c] = f2bf(a1);
    if (i0 + 2 < n) out[(size_t)(i0 + 2) * 128 + c] = f2bf(a2);
    if (i0 + 3 < n) out[(size_t)(i0 + 3) * 128 + c] = f2bf(a3);
}

// ---------------- aggregation: 32 lanes per node, lane = 4 channels (bf16 gathers) ----------------
// out[i][:] = relu( sum_j ew[j]*hw[col[j]][:] + dis[i]^2*hw[i][:] + b[:] )

__global__ __launch_bounds__(256, 8) void k_agg(const ushort* __restrict__ hwb, const int* __restrict__ rp,
                                                const int2* __restrict__ cw, const float* __restrict__ dis,
                                                const float* __restrict__ bias, float* __restrict__ out, int n) {
    int node = (int)((blockIdx.x * 256 + threadIdx.x) >> 5);
    if (node >= n) return;
    int lane = threadIdx.x & 31;
    int c4 = lane << 2;
    int s = rp[node], e = rp[node + 1];
    float ax = 0.f, ay = 0.f, az = 0.f, aw = 0.f;
    float bx = 0.f, by = 0.f, bz = 0.f, bw = 0.f;
    int j = s;
    for (; j + 3 < e; j += 4) {
        int2 p0 = cw[j], p1 = cw[j + 1], p2 = cw[j + 2], p3 = cw[j + 3];
        uint2 q0 = *(const uint2*)(hwb + ((size_t)p0.x << 7) + c4);
        uint2 q1 = *(const uint2*)(hwb + ((size_t)p1.x << 7) + c4);
        uint2 q2 = *(const uint2*)(hwb + ((size_t)p2.x << 7) + c4);
        uint2 q3 = *(const uint2*)(hwb + ((size_t)p3.x << 7) + c4);
        float w0 = __int_as_float(p0.y), w1 = __int_as_float(p1.y);
        float w2 = __int_as_float(p2.y), w3 = __int_as_float(p3.y);
        ax += bf_lo(q0.x) * w0; ay += bf_hi(q0.x) * w0; az += bf_lo(q0.y) * w0; aw += bf_hi(q0.y) * w0;
        bx += bf_lo(q1.x) * w1; by += bf_hi(q1.x) * w1; bz += bf_lo(q1.y) * w1; bw += bf_hi(q1.y) * w1;
        ax += bf_lo(q2.x) * w2; ay += bf_hi(q2.x) * w2; az += bf_lo(q2.y) * w2; aw += bf_hi(q2.y) * w2;
        bx += bf_lo(q3.x) * w3; by += bf_hi(q3.x) * w3; bz += bf_lo(q3.y) * w3; bw += bf_hi(q3.y) * w3;
    }
    for (; j < e; ++j) {
        int2 p = cw[j];
        float wj = __int_as_float(p.y);
        uint2 q = *(const uint2*)(hwb + ((size_t)p.x << 7) + c4);
        ax += bf_lo(q.x) * wj; ay += bf_hi(q.x) * wj; az += bf_lo(q.y) * wj; aw += bf_hi(q.y) * wj;
    }
    float d = dis[node];
    float sw = d * d;
    uint2 hq = *(const uint2*)(hwb + ((size_t)node << 7) + c4);
    float4 bv = *(const float4*)(bias + c4);
    float4 r;
    r.x = fmaxf(ax + bx + bf_lo(hq.x) * sw + bv.x, 0.f);
    r.y = fmaxf(ay + by + bf_hi(hq.x) * sw + bv.y, 0.f);
    r.z = fmaxf(az + bz + bf_lo(hq.y) * sw + bv.z, 0.f);
    r.w = fmaxf(aw + bw + bf_hi(hq.y) * sw + bv.w, 0.f);
    *(float4*)(out + ((size_t)node << 7) + c4) = r;
}

// ---------------- fused mean-pool + heads ----------------

__global__ __launch_bounds__(256) void k_pool_head(const float* __restrict__ h, const int* __restrict__ batch,
                                                   const float* __restrict__ Wmu, const float* __restrict__ bmu,
                                                   const float* __restrict__ Wlv, const float* __restrict__ blv,
                                                   float* __restrict__ out, int n) {
    int g = blockIdx.x;
    int t = threadIdx.x;
    int lo = 0, hi = n;
    while (lo < hi) { int m = (lo + hi) >> 1; if (batch[m] < g) lo = m + 1; else hi = m; }
    int start = lo;
    hi = n;
    while (lo < hi) { int m = (lo + hi) >> 1; if (batch[m] < g + 1) lo = m + 1; else hi = m; }
    int end = lo;

    __shared__ float sh[256];
    __shared__ float pooled[128];
    int c = t & 127, half = t >> 7;
    float acc = 0.f;
    for (int i = start + half; i < end; i += 2) acc += h[(size_t)i * 128 + c];
    sh[t] = acc;
    __syncthreads();
    if (t < 128) {
        float cnt = (float)(end - start);
        float inv = 1.0f / fmaxf(cnt, 1.0f);
        pooled[t] = (sh[t] + sh[t + 128]) * inv;
    }
    __syncthreads();
    float amu = bmu[t], alv = blv[t];
    for (int k = 0; k < 128; k += 4) {
        float p0 = pooled[k], p1 = pooled[k + 1], p2 = pooled[k + 2], p3 = pooled[k + 3];
        amu += p0 * Wmu[(k + 0) * 256 + t] + p1 * Wmu[(k + 1) * 256 + t]
             + p2 * Wmu[(k + 2) * 256 + t] + p3 * Wmu[(k + 3) * 256 + t];
        alv += p0 * Wlv[(k + 0) * 256 + t] + p1 * Wlv[(k + 1) * 256 + t]
             + p2 * Wlv[(k + 2) * 256 + t] + p3 * Wlv[(k + 3) * 256 + t];
    }
    out[(size_t)g * 256 + t] = amu;
    out[(size_t)N_GRAPHS * 256 + (size_t)g * 256 + t] = alv;
}

// ---------------- launch ----------------

extern "C" void kernel_launch(void* const* d_in, const int* in_sizes, int n_in,
                              void* d_out, int out_size, void* d_ws, size_t ws_size,
                              hipStream_t stream) {
    const float* x    = (const float*)d_in[0];
    const int*   eidx = (const int*)d_in[1];
    const int*   batch= (const int*)d_in[2];
    const float* W1   = (const float*)d_in[3];
    const float* b1   = (const float*)d_in[4];
    const float* W2   = (const float*)d_in[5];
    const float* b2   = (const float*)d_in[6];
    const float* W3   = (const float*)d_in[7];
    const float* b3   = (const float*)d_in[8];
    const float* Wmu  = (const float*)d_in[9];
    const float* bmu  = (const float*)d_in[10];
    const float* Wlv  = (const float*)d_in[11];
    const float* blv  = (const float*)d_in[12];
    float* out = (float*)d_out;

    const int N = N_NODES, E = N_EDGES;
    const int* srcp = eidx;
    const int* dstp = eidx + E;

    // workspace layout
    ushort* A     = (ushort*)d_ws;                  // N*128 bf16 (hw, gathered)
    float* B      = (float*)(A + (size_t)N * 128);  // N*128 fp32 (h)
    float* dis    = B + (size_t)N * 128;            // N
    int*   hist   = (int*)(dis + N);                // N
    int*   row_ptr= hist + N;                       // N+2 (pad even)
    int*   cursor = row_ptr + (N + 2);              // N
    int*   partials = cursor + N;                   // 128
    int2*  cw     = (int2*)(partials + 128);        // E

    const int gN   = (N + 255) / 256;
    const int gE   = (E + 255) / 256;
    const int nScanBlocks = (N + 1023) / 1024;

    // CSR build
    k_zero_int<<<gN, 256, 0, stream>>>(hist, N);
    k_hist<<<gE, 256, 0, stream>>>(dstp, hist, E);
    k_dis<<<gN, 256, 0, stream>>>(hist, dis, N);
    k_scan1<<<nScanBlocks, 256, 0, stream>>>(hist, row_ptr, partials, N);
    k_scan2<<<1, 128, 0, stream>>>(partials, nScanBlocks);
    k_scan3<<<gN, 256, 0, stream>>>(hist, row_ptr, partials, cursor, N, E);
    k_scatter<<<gE, 256, 0, stream>>>(srcp, dstp, dis, cursor, cw, E);

    const int gGemm = (N + 31) / 32;
    const int gAgg  = (N + 7) / 8;

    k_gemm<IN_DIM><<<gGemm, 1024, 0, stream>>>(x, W1, A, N);
    k_agg<<<gAgg, 256, 0, stream>>>(A, row_ptr, cw, dis, b1, B, N);
    k_gemm<HID><<<gGemm, 1024, 0, stream>>>(B, W2, A, N);
    k_agg<<<gAgg, 256, 0, stream>>>(A, row_ptr, cw, dis, b2, B, N);
    k_gemm<HID><<<gGemm, 1024, 0, stream>>>(B, W3, A, N);
    k_agg<<<gAgg, 256, 0, stream>>>(A, row_ptr, cw, dis, b3, B, N);
    k_pool_head<<<N_GRAPHS, 256, 0, stream>>>(B, batch, Wmu, bmu, Wlv, blv, out, N);
}

// Round 4
// 848.610 us; speedup vs baseline: 2.2735x; 1.4390x over previous
//
#include <hip/hip_runtime.h>
#include <hip/hip_bf16.h>

#define N_NODES 100000
#define N_EDGES 3200000
#define N_GRAPHS 512
#define IN_DIM 29
#define HID 128
#define LAT 256

typedef unsigned int uint;
typedef unsigned short ushort;
typedef float v4f __attribute__((ext_vector_type(4)));
typedef short v8s __attribute__((ext_vector_type(8)));

// round-to-nearest-even fp32 -> bf16 (finite inputs)
__device__ __forceinline__ ushort f2bf(float f) {
    uint u = __float_as_uint(f);
    return (ushort)((u + 0x7FFFu + ((u >> 16) & 1u)) >> 16);
}
__device__ __forceinline__ float bf2f(ushort h) { return __uint_as_float(((uint)h) << 16); }
__device__ __forceinline__ float bf_lo(uint p) { return __uint_as_float(p << 16); }
__device__ __forceinline__ float bf_hi(uint p) { return __uint_as_float(p & 0xFFFF0000u); }

// ---------------- preprocessing: degree, CSR build ----------------

__global__ __launch_bounds__(256) void k_zero_int(int* p, int n) {
    int i = blockIdx.x * 256 + threadIdx.x;
    if (i < n) p[i] = 0;
}

__global__ __launch_bounds__(256) void k_hist(const int* __restrict__ dst, int* __restrict__ hist, int e) {
    int i = blockIdx.x * 256 + threadIdx.x;
    if (i < e) atomicAdd(&hist[dst[i]], 1);
}

__global__ __launch_bounds__(256) void k_dis(const int* __restrict__ hist, float* __restrict__ dis, int n) {
    int i = blockIdx.x * 256 + threadIdx.x;
    if (i < n) dis[i] = rsqrtf((float)hist[i] + 1.0f);
}

__global__ __launch_bounds__(256) void k_scan1(const int* __restrict__ hist, int* __restrict__ incl,
                                               int* __restrict__ partials, int n) {
    __shared__ int sh[256];
    int t = threadIdx.x;
    int base = blockIdx.x * 1024 + t * 4;
    int v0 = (base + 0 < n) ? hist[base + 0] : 0;
    int v1 = (base + 1 < n) ? hist[base + 1] : 0;
    int v2 = (base + 2 < n) ? hist[base + 2] : 0;
    int v3 = (base + 3 < n) ? hist[base + 3] : 0;
    int s = v0 + v1 + v2 + v3;
    sh[t] = s;
    __syncthreads();
    for (int off = 1; off < 256; off <<= 1) {
        int x = (t >= off) ? sh[t - off] : 0;
        __syncthreads();
        sh[t] += x;
        __syncthreads();
    }
    int excl = sh[t] - s;
    int run = excl;
    run += v0; if (base + 0 < n) incl[base + 0] = run;
    run += v1; if (base + 1 < n) incl[base + 1] = run;
    run += v2; if (base + 2 < n) incl[base + 2] = run;
    run += v3; if (base + 3 < n) incl[base + 3] = run;
    if (t == 0) partials[blockIdx.x] = sh[255];
}

__global__ __launch_bounds__(128) void k_scan2(int* partials, int np) {
    __shared__ int sh[128];
    int t = threadIdx.x;
    if (t < np) sh[t] = partials[t];
    __syncthreads();
    if (t == 0) {
        int run = 0;
        for (int i = 0; i < np; ++i) { int v = sh[i]; sh[i] = run; run += v; }
    }
    __syncthreads();
    if (t < np) partials[t] = sh[t];
}

__global__ __launch_bounds__(256) void k_scan3(const int* __restrict__ hist, int* __restrict__ rp,
                                               const int* __restrict__ partials, int* __restrict__ cursor,
                                               int n, int total) {
    int i = blockIdx.x * 256 + threadIdx.x;
    if (i < n) {
        int excl = rp[i] - hist[i] + partials[i >> 10];
        rp[i] = excl;
        cursor[i] = excl;
    }
    if (i == n) rp[n] = total;
}

__global__ __launch_bounds__(256) void k_scatter(const int* __restrict__ src, const int* __restrict__ dst,
                                                 const float* __restrict__ dis, int* __restrict__ cursor,
                                                 int2* __restrict__ cw, int e) {
    int i = blockIdx.x * 256 + threadIdx.x;
    if (i < e) {
        int s = src[i], d = dst[i];
        int pos = atomicAdd(&cursor[d], 1);
        int2 p; p.x = s; p.y = __float_as_int(dis[s] * dis[d]);
        cw[pos] = p;
    }
}

// ---------------- W pack: fp32 [Ksrc][128] -> hi/lo bf16 planes in B-fragment order ----------------
// layout index = ((kstep*8 + ntile)*64 + lane)*8 + j ; element = W[kstep*32 + (lane>>4)*8 + j][ntile*16 + (lane&15)]

__global__ __launch_bounds__(256) void k_pack(const float* __restrict__ W, ushort* __restrict__ hi,
                                              ushort* __restrict__ lo, int Ksrc, int total) {
    int idx = blockIdx.x * 256 + threadIdx.x;
    if (idx >= total) return;
    int j = idx & 7;
    int lane = (idx >> 3) & 63;
    int nt = (idx >> 9) & 7;
    int ks = idx >> 12;
    int k = ks * 32 + (lane >> 4) * 8 + j;
    int n = nt * 16 + (lane & 15);
    float v = (k < Ksrc) ? W[k * 128 + n] : 0.f;
    ushort h = f2bf(v);
    ushort l = f2bf(v - bf2f(h));
    hi[idx] = h;
    lo[idx] = l;
}

// ---------------- MFMA GEMM: out_bf16[n][128] = in_f32[n][KSRC] @ W ----------------
// Split precision: acc = Ahi@Whi + Ahi@Wlo + Alo@Whi  (fp32-equivalent).
// Block = 256 threads = 4 waves; wave owns 16 rows x 128 cols (8 16x16 tiles).

template <int KSTEPS, int KSRC>
__global__ __launch_bounds__(256, 4) void k_gemm_mfma(const float* __restrict__ in,
                                                      const ushort* __restrict__ Whi,
                                                      const ushort* __restrict__ Wlo,
                                                      ushort* __restrict__ out, int n) {
    const int wave = threadIdx.x >> 6;
    const int lane = threadIdx.x & 63;
    const int m0 = (blockIdx.x * 4 + wave) * 16;
    if (m0 >= n) return;
    int row = m0 + (lane & 15);
    if (row >= n) row = n - 1;
    const int kh = (lane >> 4) * 8;
    const float* rptr = in + (size_t)row * KSRC + kh;

    v4f acc[8];
    #pragma unroll
    for (int t = 0; t < 8; ++t) acc[t] = (v4f){0.f, 0.f, 0.f, 0.f};

    #pragma unroll
    for (int ks = 0; ks < KSTEPS; ++ks) {
        float a[8];
        if constexpr (KSRC == IN_DIM) {
            #pragma unroll
            for (int j = 0; j < 8; ++j) a[j] = (kh + j < KSRC) ? rptr[j] : 0.f;
        } else {
            float4 p0 = *(const float4*)(rptr + ks * 32);
            float4 p1 = *(const float4*)(rptr + ks * 32 + 4);
            a[0] = p0.x; a[1] = p0.y; a[2] = p0.z; a[3] = p0.w;
            a[4] = p1.x; a[5] = p1.y; a[6] = p1.z; a[7] = p1.w;
        }
        v8s ahi, alo;
        #pragma unroll
        for (int j = 0; j < 8; ++j) {
            ushort h = f2bf(a[j]);
            ushort l = f2bf(a[j] - bf2f(h));
            ahi[j] = (short)h;
            alo[j] = (short)l;
        }
        const ushort* bh = Whi + (size_t)(ks * 8) * 512 + (size_t)lane * 8;
        const ushort* bl = Wlo + (size_t)(ks * 8) * 512 + (size_t)lane * 8;
        #pragma unroll
        for (int nt = 0; nt < 8; ++nt) {
            v8s bhi = *(const v8s*)(bh + nt * 512);
            v8s blo = *(const v8s*)(bl + nt * 512);
            acc[nt] = __builtin_amdgcn_mfma_f32_16x16x32_bf16(ahi, bhi, acc[nt], 0, 0, 0);
            acc[nt] = __builtin_amdgcn_mfma_f32_16x16x32_bf16(ahi, blo, acc[nt], 0, 0, 0);
            acc[nt] = __builtin_amdgcn_mfma_f32_16x16x32_bf16(alo, bhi, acc[nt], 0, 0, 0);
        }
    }

    // C/D layout: col = lane&15, row = (lane>>4)*4 + reg
    const int orow0 = m0 + (lane >> 4) * 4;
    const int col0 = lane & 15;
    #pragma unroll
    for (int nt = 0; nt < 8; ++nt) {
        #pragma unroll
        for (int r = 0; r < 4; ++r) {
            int orow = orow0 + r;
            if (orow < n) out[(size_t)orow * 128 + nt * 16 + col0] = f2bf(acc[nt][r]);
        }
    }
}

// ---------------- aggregation: 32 lanes per node, lane = 4 channels (bf16 gathers) ----------------

__global__ __launch_bounds__(256, 8) void k_agg(const ushort* __restrict__ hwb, const int* __restrict__ rp,
                                                const int2* __restrict__ cw, const float* __restrict__ dis,
                                                const float* __restrict__ bias, float* __restrict__ out, int n) {
    int node = (int)((blockIdx.x * 256 + threadIdx.x) >> 5);
    if (node >= n) return;
    int lane = threadIdx.x & 31;
    int c4 = lane << 2;
    int s = rp[node], e = rp[node + 1];
    float ax = 0.f, ay = 0.f, az = 0.f, aw = 0.f;
    float bx = 0.f, by = 0.f, bz = 0.f, bw = 0.f;
    int j = s;
    for (; j + 3 < e; j += 4) {
        int2 p0 = cw[j], p1 = cw[j + 1], p2 = cw[j + 2], p3 = cw[j + 3];
        uint2 q0 = *(const uint2*)(hwb + ((size_t)p0.x << 7) + c4);
        uint2 q1 = *(const uint2*)(hwb + ((size_t)p1.x << 7) + c4);
        uint2 q2 = *(const uint2*)(hwb + ((size_t)p2.x << 7) + c4);
        uint2 q3 = *(const uint2*)(hwb + ((size_t)p3.x << 7) + c4);
        float w0 = __int_as_float(p0.y), w1 = __int_as_float(p1.y);
        float w2 = __int_as_float(p2.y), w3 = __int_as_float(p3.y);
        ax += bf_lo(q0.x) * w0; ay += bf_hi(q0.x) * w0; az += bf_lo(q0.y) * w0; aw += bf_hi(q0.y) * w0;
        bx += bf_lo(q1.x) * w1; by += bf_hi(q1.x) * w1; bz += bf_lo(q1.y) * w1; bw += bf_hi(q1.y) * w1;
        ax += bf_lo(q2.x) * w2; ay += bf_hi(q2.x) * w2; az += bf_lo(q2.y) * w2; aw += bf_hi(q2.y) * w2;
        bx += bf_lo(q3.x) * w3; by += bf_hi(q3.x) * w3; bz += bf_lo(q3.y) * w3; bw += bf_hi(q3.y) * w3;
    }
    for (; j < e; ++j) {
        int2 p = cw[j];
        float wj = __int_as_float(p.y);
        uint2 q = *(const uint2*)(hwb + ((size_t)p.x << 7) + c4);
        ax += bf_lo(q.x) * wj; ay += bf_hi(q.x) * wj; az += bf_lo(q.y) * wj; aw += bf_hi(q.y) * wj;
    }
    float d = dis[node];
    float sw = d * d;
    uint2 hq = *(const uint2*)(hwb + ((size_t)node << 7) + c4);
    float4 bv = *(const float4*)(bias + c4);
    float4 r;
    r.x = fmaxf(ax + bx + bf_lo(hq.x) * sw + bv.x, 0.f);
    r.y = fmaxf(ay + by + bf_hi(hq.x) * sw + bv.y, 0.f);
    r.z = fmaxf(az + bz + bf_lo(hq.y) * sw + bv.z, 0.f);
    r.w = fmaxf(aw + bw + bf_hi(hq.y) * sw + bv.w, 0.f);
    *(float4*)(out + ((size_t)node << 7) + c4) = r;
}

// ---------------- fused mean-pool + heads ----------------

__global__ __launch_bounds__(256) void k_pool_head(const float* __restrict__ h, const int* __restrict__ batch,
                                                   const float* __restrict__ Wmu, const float* __restrict__ bmu,
                                                   const float* __restrict__ Wlv, const float* __restrict__ blv,
                                                   float* __restrict__ out, int n) {
    int g = blockIdx.x;
    int t = threadIdx.x;
    int lo = 0, hi = n;
    while (lo < hi) { int m = (lo + hi) >> 1; if (batch[m] < g) lo = m + 1; else hi = m; }
    int start = lo;
    hi = n;
    while (lo < hi) { int m = (lo + hi) >> 1; if (batch[m] < g + 1) lo = m + 1; else hi = m; }
    int end = lo;

    __shared__ float sh[256];
    __shared__ float pooled[128];
    int c = t & 127, half = t >> 7;
    float acc = 0.f;
    for (int i = start + half; i < end; i += 2) acc += h[(size_t)i * 128 + c];
    sh[t] = acc;
    __syncthreads();
    if (t < 128) {
        float cnt = (float)(end - start);
        float inv = 1.0f / fmaxf(cnt, 1.0f);
        pooled[t] = (sh[t] + sh[t + 128]) * inv;
    }
    __syncthreads();
    float amu = bmu[t], alv = blv[t];
    for (int k = 0; k < 128; k += 4) {
        float p0 = pooled[k], p1 = pooled[k + 1], p2 = pooled[k + 2], p3 = pooled[k + 3];
        amu += p0 * Wmu[(k + 0) * 256 + t] + p1 * Wmu[(k + 1) * 256 + t]
             + p2 * Wmu[(k + 2) * 256 + t] + p3 * Wmu[(k + 3) * 256 + t];
        alv += p0 * Wlv[(k + 0) * 256 + t] + p1 * Wlv[(k + 1) * 256 + t]
             + p2 * Wlv[(k + 2) * 256 + t] + p3 * Wlv[(k + 3) * 256 + t];
    }
    out[(size_t)g * 256 + t] = amu;
    out[(size_t)N_GRAPHS * 256 + (size_t)g * 256 + t] = alv;
}

// ---------------- launch ----------------

extern "C" void kernel_launch(void* const* d_in, const int* in_sizes, int n_in,
                              void* d_out, int out_size, void* d_ws, size_t ws_size,
                              hipStream_t stream) {
    const float* x    = (const float*)d_in[0];
    const int*   eidx = (const int*)d_in[1];
    const int*   batch= (const int*)d_in[2];
    const float* W1   = (const float*)d_in[3];
    const float* b1   = (const float*)d_in[4];
    const float* W2   = (const float*)d_in[5];
    const float* b2   = (const float*)d_in[6];
    const float* W3   = (const float*)d_in[7];
    const float* b3   = (const float*)d_in[8];
    const float* Wmu  = (const float*)d_in[9];
    const float* bmu  = (const float*)d_in[10];
    const float* Wlv  = (const float*)d_in[11];
    const float* blv  = (const float*)d_in[12];
    float* out = (float*)d_out;

    const int N = N_NODES, E = N_EDGES;
    const int* srcp = eidx;
    const int* dstp = eidx + E;

    // workspace layout (16B-aligned chunks first)
    ushort* w1h = (ushort*)d_ws;            // 4096
    ushort* w1l = w1h + 4096;               // 4096
    ushort* w2h = w1l + 4096;               // 16384
    ushort* w2l = w2h + 16384;              // 16384
    ushort* w3h = w2l + 16384;              // 16384
    ushort* w3l = w3h + 16384;              // 16384
    ushort* A   = w3l + 16384;              // N*128 bf16 (hw, gathered)
    float*  B   = (float*)(A + (size_t)N * 128);  // N*128 fp32 (h)
    float*  dis = B + (size_t)N * 128;      // N
    int*   hist = (int*)(dis + N);          // N
    int*   row_ptr = hist + N;              // N+2 (pad even)
    int*   cursor  = row_ptr + (N + 2);     // N
    int*   partials = cursor + N;           // 128
    int2*  cw   = (int2*)(partials + 128);  // E

    const int gN   = (N + 255) / 256;
    const int gE   = (E + 255) / 256;
    const int nScanBlocks = (N + 1023) / 1024;

    // CSR build
    k_zero_int<<<gN, 256, 0, stream>>>(hist, N);
    k_hist<<<gE, 256, 0, stream>>>(dstp, hist, E);
    k_dis<<<gN, 256, 0, stream>>>(hist, dis, N);
    k_scan1<<<nScanBlocks, 256, 0, stream>>>(hist, row_ptr, partials, N);
    k_scan2<<<1, 128, 0, stream>>>(partials, nScanBlocks);
    k_scan3<<<gN, 256, 0, stream>>>(hist, row_ptr, partials, cursor, N, E);
    k_scatter<<<gE, 256, 0, stream>>>(srcp, dstp, dis, cursor, cw, E);

    // W packs (fragment-order hi/lo planes)
    k_pack<<<16, 256, 0, stream>>>(W1, w1h, w1l, IN_DIM, 4096);
    k_pack<<<64, 256, 0, stream>>>(W2, w2h, w2l, HID, 16384);
    k_pack<<<64, 256, 0, stream>>>(W3, w3h, w3l, HID, 16384);

    const int gGemm = (N + 63) / 64;   // 4 waves x 16 rows per block
    const int gAgg  = (N + 7) / 8;

    k_gemm_mfma<1, IN_DIM><<<gGemm, 256, 0, stream>>>(x, w1h, w1l, A, N);
    k_agg<<<gAgg, 256, 0, stream>>>(A, row_ptr, cw, dis, b1, B, N);
    k_gemm_mfma<4, HID><<<gGemm, 256, 0, stream>>>(B, w2h, w2l, A, N);
    k_agg<<<gAgg, 256, 0, stream>>>(A, row_ptr, cw, dis, b2, B, N);
    k_gemm_mfma<4, HID><<<gGemm, 256, 0, stream>>>(B, w3h, w3l, A, N);
    k_agg<<<gAgg, 256, 0, stream>>>(A, row_ptr, cw, dis, b3, B, N);
    k_pool_head<<<N_GRAPHS, 256, 0, stream>>>(B, batch, Wmu, bmu, Wlv, blv, out, N);
}

// Round 5
// 759.642 us; speedup vs baseline: 2.5398x; 1.1171x over previous
//
#include <hip/hip_runtime.h>
#include <hip/hip_bf16.h>

#define N_NODES 100000
#define N_EDGES 3200000
#define N_GRAPHS 512
#define IN_DIM 29
#define HID 128
#define LAT 256
#define NB 391   // ceil(N_NODES/256) dst-buckets

typedef unsigned int uint;
typedef unsigned short ushort;
typedef float v4f __attribute__((ext_vector_type(4)));
typedef short v8s __attribute__((ext_vector_type(8)));

// round-to-nearest-even fp32 -> bf16 (finite inputs)
__device__ __forceinline__ ushort f2bf(float f) {
    uint u = __float_as_uint(f);
    return (ushort)((u + 0x7FFFu + ((u >> 16) & 1u)) >> 16);
}
__device__ __forceinline__ float bf2f(ushort h) { return __uint_as_float(((uint)h) << 16); }
__device__ __forceinline__ float bf_lo(uint p) { return __uint_as_float(p << 16); }
__device__ __forceinline__ float bf_hi(uint p) { return __uint_as_float(p & 0xFFFF0000u); }

__device__ __forceinline__ void bfadd(float* a, uint4 q) {
    a[0] += bf_lo(q.x); a[1] += bf_hi(q.x);
    a[2] += bf_lo(q.y); a[3] += bf_hi(q.y);
    a[4] += bf_lo(q.z); a[5] += bf_hi(q.z);
    a[6] += bf_lo(q.w); a[7] += bf_hi(q.w);
}

// ---------------- preprocessing: degree, rp ----------------

__global__ __launch_bounds__(256) void k_zero_int(int* p, int n) {
    int i = blockIdx.x * 256 + threadIdx.x;
    if (i < n) p[i] = 0;
}

__global__ __launch_bounds__(256) void k_hist(const int* __restrict__ dst, int* __restrict__ hist, int e) {
    int i = blockIdx.x * 256 + threadIdx.x;
    if (i < e) atomicAdd(&hist[dst[i]], 1);
}

__global__ __launch_bounds__(256) void k_dis(const int* __restrict__ hist, float* __restrict__ dis, int n) {
    int i = blockIdx.x * 256 + threadIdx.x;
    if (i < n) dis[i] = rsqrtf((float)hist[i] + 1.0f);
}

__global__ __launch_bounds__(256) void k_scan1(const int* __restrict__ hist, int* __restrict__ incl,
                                               int* __restrict__ partials, int n) {
    __shared__ int sh[256];
    int t = threadIdx.x;
    int base = blockIdx.x * 1024 + t * 4;
    int v0 = (base + 0 < n) ? hist[base + 0] : 0;
    int v1 = (base + 1 < n) ? hist[base + 1] : 0;
    int v2 = (base + 2 < n) ? hist[base + 2] : 0;
    int v3 = (base + 3 < n) ? hist[base + 3] : 0;
    int s = v0 + v1 + v2 + v3;
    sh[t] = s;
    __syncthreads();
    for (int off = 1; off < 256; off <<= 1) {
        int x = (t >= off) ? sh[t - off] : 0;
        __syncthreads();
        sh[t] += x;
        __syncthreads();
    }
    int excl = sh[t] - s;
    int run = excl;
    run += v0; if (base + 0 < n) incl[base + 0] = run;
    run += v1; if (base + 1 < n) incl[base + 1] = run;
    run += v2; if (base + 2 < n) incl[base + 2] = run;
    run += v3; if (base + 3 < n) incl[base + 3] = run;
    if (t == 0) partials[blockIdx.x] = sh[255];
}

__global__ __launch_bounds__(128) void k_scan2(int* partials, int np) {
    __shared__ int sh[128];
    int t = threadIdx.x;
    if (t < np) sh[t] = partials[t];
    __syncthreads();
    if (t == 0) {
        int run = 0;
        for (int i = 0; i < np; ++i) { int v = sh[i]; sh[i] = run; run += v; }
    }
    __syncthreads();
    if (t < np) partials[t] = sh[t];
}

__global__ __launch_bounds__(256) void k_scan3(const int* __restrict__ hist, int* __restrict__ rp,
                                               const int* __restrict__ partials, int n, int total) {
    int i = blockIdx.x * 256 + threadIdx.x;
    if (i < n) rp[i] = rp[i] - hist[i] + partials[i >> 10];
    if (i == n) rp[n] = total;
}

// ---------------- two-phase binned CSR build ----------------

__global__ __launch_bounds__(256) void k_binit(const int* __restrict__ rp, int* __restrict__ bktCursor) {
    int b = blockIdx.x * 256 + threadIdx.x;
    if (b < NB) bktCursor[b] = rp[b << 8];
}

// Phase A: bin edges by dst>>8; pack (dst&255)<<17 | src
__global__ __launch_bounds__(256, 4) void k_binA(const int* __restrict__ src, const int* __restrict__ dst,
                                                 int* __restrict__ bktCursor, int* __restrict__ packed, int e) {
    __shared__ int hist[NB];
    __shared__ int base[NB];
    for (int i = threadIdx.x; i < NB; i += 256) hist[i] = 0;
    __syncthreads();
    int d[16], s[16];
    const int blockStart = blockIdx.x * 4096;
    #pragma unroll
    for (int t = 0; t < 16; ++t) {
        int idx = blockStart + t * 256 + threadIdx.x;
        if (idx < e) {
            d[t] = dst[idx];
            s[t] = src[idx];
            atomicAdd(&hist[d[t] >> 8], 1);
        } else d[t] = -1;
    }
    __syncthreads();
    for (int i = threadIdx.x; i < NB; i += 256) {
        int c = hist[i];
        base[i] = c ? atomicAdd(&bktCursor[i], c) : 0;
    }
    __syncthreads();
    #pragma unroll
    for (int t = 0; t < 16; ++t) {
        if (d[t] >= 0) {
            int b = d[t] >> 8;
            int pos = atomicAdd(&base[b], 1);
            packed[pos] = ((d[t] & 255) << 17) | s[t];
        }
    }
}

// Phase B: per-bucket scatter to final CSR positions (L2-resident region)
__global__ __launch_bounds__(256, 4) void k_binB(const int* __restrict__ rp, const int* __restrict__ packed,
                                                 int* __restrict__ col, int n) {
    const int b = blockIdx.x;
    const int nodeBase = b << 8;
    __shared__ int cur[256];
    int t = threadIdx.x;
    int node = nodeBase + t;
    cur[t] = (node < n) ? rp[node] : 0;
    int nEnd = nodeBase + 256; if (nEnd > n) nEnd = n;
    const int segStart = rp[nodeBase];
    const int segEnd = rp[nEnd];
    __syncthreads();
    for (int j = segStart + t; j < segEnd; j += 256) {
        int pk = packed[j];
        int dl = pk >> 17;
        int pos = atomicAdd(&cur[dl], 1);
        col[pos] = pk & 0x1FFFF;
    }
}

// ---------------- W pack: fp32 [Ksrc][128] -> hi/lo bf16 planes in B-fragment order ----------------

__global__ __launch_bounds__(256) void k_pack(const float* __restrict__ W, ushort* __restrict__ hi,
                                              ushort* __restrict__ lo, int Ksrc, int total) {
    int idx = blockIdx.x * 256 + threadIdx.x;
    if (idx >= total) return;
    int j = idx & 7;
    int lane = (idx >> 3) & 63;
    int nt = (idx >> 9) & 7;
    int ks = idx >> 12;
    int k = ks * 32 + (lane >> 4) * 8 + j;
    int n = nt * 16 + (lane & 15);
    float v = (k < Ksrc) ? W[k * 128 + n] : 0.f;
    ushort h = f2bf(v);
    ushort l = f2bf(v - bf2f(h));
    hi[idx] = h;
    lo[idx] = l;
}

// ---------------- MFMA GEMM: hws_bf16[n][128] = dis[n] * (in_f32[n][KSRC] @ W) ----------------
// Split precision: acc = Ahi@Whi + Ahi@Wlo + Alo@Whi.

template <int KSTEPS, int KSRC>
__global__ __launch_bounds__(256, 4) void k_gemm_mfma(const float* __restrict__ in,
                                                      const ushort* __restrict__ Whi,
                                                      const ushort* __restrict__ Wlo,
                                                      const float* __restrict__ dis,
                                                      ushort* __restrict__ out, int n) {
    const int wave = threadIdx.x >> 6;
    const int lane = threadIdx.x & 63;
    const int m0 = (blockIdx.x * 4 + wave) * 16;
    if (m0 >= n) return;
    int row = m0 + (lane & 15);
    if (row >= n) row = n - 1;
    const int kh = (lane >> 4) * 8;
    const float* rptr = in + (size_t)row * KSRC + kh;

    v4f acc[8];
    #pragma unroll
    for (int t = 0; t < 8; ++t) acc[t] = (v4f){0.f, 0.f, 0.f, 0.f};

    #pragma unroll
    for (int ks = 0; ks < KSTEPS; ++ks) {
        float a[8];
        if constexpr (KSRC == IN_DIM) {
            #pragma unroll
            for (int j = 0; j < 8; ++j) a[j] = (kh + j < KSRC) ? rptr[j] : 0.f;
        } else {
            float4 p0 = *(const float4*)(rptr + ks * 32);
            float4 p1 = *(const float4*)(rptr + ks * 32 + 4);
            a[0] = p0.x; a[1] = p0.y; a[2] = p0.z; a[3] = p0.w;
            a[4] = p1.x; a[5] = p1.y; a[6] = p1.z; a[7] = p1.w;
        }
        v8s ahi, alo;
        #pragma unroll
        for (int j = 0; j < 8; ++j) {
            ushort h = f2bf(a[j]);
            ushort l = f2bf(a[j] - bf2f(h));
            ahi[j] = (short)h;
            alo[j] = (short)l;
        }
        const ushort* bh = Whi + (size_t)(ks * 8) * 512 + (size_t)lane * 8;
        const ushort* bl = Wlo + (size_t)(ks * 8) * 512 + (size_t)lane * 8;
        #pragma unroll
        for (int nt = 0; nt < 8; ++nt) {
            v8s bhi = *(const v8s*)(bh + nt * 512);
            v8s blo = *(const v8s*)(bl + nt * 512);
            acc[nt] = __builtin_amdgcn_mfma_f32_16x16x32_bf16(ahi, bhi, acc[nt], 0, 0, 0);
            acc[nt] = __builtin_amdgcn_mfma_f32_16x16x32_bf16(ahi, blo, acc[nt], 0, 0, 0);
            acc[nt] = __builtin_amdgcn_mfma_f32_16x16x32_bf16(alo, bhi, acc[nt], 0, 0, 0);
        }
    }

    // C/D layout: col = lane&15, row = (lane>>4)*4 + reg ; scale by dis[row]
    const int orow0 = m0 + (lane >> 4) * 4;
    const int col0 = lane & 15;
    #pragma unroll
    for (int r = 0; r < 4; ++r) {
        int orow = orow0 + r;
        if (orow < n) {
            float dv = dis[orow];
            #pragma unroll
            for (int nt = 0; nt < 8; ++nt)
                out[(size_t)orow * 128 + nt * 16 + col0] = f2bf(acc[nt][r] * dv);
        }
    }
}

// ---------------- aggregation: 16 lanes/node, 8 ch/lane, unweighted gather-sum ----------------
// out[i][:] = relu( dis[i] * ( sum_j hws[col[j]][:] + hws[i][:] ) + b[:] )

__global__ __launch_bounds__(256, 8) void k_agg(const ushort* __restrict__ hws, const int* __restrict__ rp,
                                                const int* __restrict__ col, const float* __restrict__ dis,
                                                const float* __restrict__ bias, float* __restrict__ out, int n) {
    int node = (int)((blockIdx.x * 256 + threadIdx.x) >> 4);
    if (node >= n) return;
    int c8 = (threadIdx.x & 15) << 3;
    int s = rp[node], e = rp[node + 1];
    float A[8] = {0.f, 0.f, 0.f, 0.f, 0.f, 0.f, 0.f, 0.f};
    float B[8] = {0.f, 0.f, 0.f, 0.f, 0.f, 0.f, 0.f, 0.f};
    int j = s;
    for (; j + 3 < e; j += 4) {
        int c0 = col[j], c1 = col[j + 1], c2 = col[j + 2], c3 = col[j + 3];
        uint4 q0 = *(const uint4*)(hws + ((size_t)c0 << 7) + c8);
        uint4 q1 = *(const uint4*)(hws + ((size_t)c1 << 7) + c8);
        uint4 q2 = *(const uint4*)(hws + ((size_t)c2 << 7) + c8);
        uint4 q3 = *(const uint4*)(hws + ((size_t)c3 << 7) + c8);
        bfadd(A, q0); bfadd(B, q1); bfadd(A, q2); bfadd(B, q3);
    }
    for (; j < e; ++j) {
        int c = col[j];
        uint4 q = *(const uint4*)(hws + ((size_t)c << 7) + c8);
        bfadd(A, q);
    }
    uint4 qs = *(const uint4*)(hws + ((size_t)node << 7) + c8);
    bfadd(A, qs);
    float dv = dis[node];
    float4 bv0 = *(const float4*)(bias + c8);
    float4 bv1 = *(const float4*)(bias + c8 + 4);
    float4 r0, r1;
    r0.x = fmaxf(dv * (A[0] + B[0]) + bv0.x, 0.f);
    r0.y = fmaxf(dv * (A[1] + B[1]) + bv0.y, 0.f);
    r0.z = fmaxf(dv * (A[2] + B[2]) + bv0.z, 0.f);
    r0.w = fmaxf(dv * (A[3] + B[3]) + bv0.w, 0.f);
    r1.x = fmaxf(dv * (A[4] + B[4]) + bv1.x, 0.f);
    r1.y = fmaxf(dv * (A[5] + B[5]) + bv1.y, 0.f);
    r1.z = fmaxf(dv * (A[6] + B[6]) + bv1.z, 0.f);
    r1.w = fmaxf(dv * (A[7] + B[7]) + bv1.w, 0.f);
    *(float4*)(out + (size_t)node * 128 + c8) = r0;
    *(float4*)(out + (size_t)node * 128 + c8 + 4) = r1;
}

// ---------------- fused mean-pool + heads ----------------

__global__ __launch_bounds__(256) void k_pool_head(const float* __restrict__ h, const int* __restrict__ batch,
                                                   const float* __restrict__ Wmu, const float* __restrict__ bmu,
                                                   const float* __restrict__ Wlv, const float* __restrict__ blv,
                                                   float* __restrict__ out, int n) {
    int g = blockIdx.x;
    int t = threadIdx.x;
    int lo = 0, hi = n;
    while (lo < hi) { int m = (lo + hi) >> 1; if (batch[m] < g) lo = m + 1; else hi = m; }
    int start = lo;
    hi = n;
    while (lo < hi) { int m = (lo + hi) >> 1; if (batch[m] < g + 1) lo = m + 1; else hi = m; }
    int end = lo;

    __shared__ float sh[256];
    __shared__ float pooled[128];
    int c = t & 127, half = t >> 7;
    float acc = 0.f;
    for (int i = start + half; i < end; i += 2) acc += h[(size_t)i * 128 + c];
    sh[t] = acc;
    __syncthreads();
    if (t < 128) {
        float cnt = (float)(end - start);
        float inv = 1.0f / fmaxf(cnt, 1.0f);
        pooled[t] = (sh[t] + sh[t + 128]) * inv;
    }
    __syncthreads();
    float amu = bmu[t], alv = blv[t];
    for (int k = 0; k < 128; k += 4) {
        float p0 = pooled[k], p1 = pooled[k + 1], p2 = pooled[k + 2], p3 = pooled[k + 3];
        amu += p0 * Wmu[(k + 0) * 256 + t] + p1 * Wmu[(k + 1) * 256 + t]
             + p2 * Wmu[(k + 2) * 256 + t] + p3 * Wmu[(k + 3) * 256 + t];
        alv += p0 * Wlv[(k + 0) * 256 + t] + p1 * Wlv[(k + 1) * 256 + t]
             + p2 * Wlv[(k + 2) * 256 + t] + p3 * Wlv[(k + 3) * 256 + t];
    }
    out[(size_t)g * 256 + t] = amu;
    out[(size_t)N_GRAPHS * 256 + (size_t)g * 256 + t] = alv;
}

// ---------------- launch ----------------

extern "C" void kernel_launch(void* const* d_in, const int* in_sizes, int n_in,
                              void* d_out, int out_size, void* d_ws, size_t ws_size,
                              hipStream_t stream) {
    const float* x    = (const float*)d_in[0];
    const int*   eidx = (const int*)d_in[1];
    const int*   batch= (const int*)d_in[2];
    const float* W1   = (const float*)d_in[3];
    const float* b1   = (const float*)d_in[4];
    const float* W2   = (const float*)d_in[5];
    const float* b2   = (const float*)d_in[6];
    const float* W3   = (const float*)d_in[7];
    const float* b3   = (const float*)d_in[8];
    const float* Wmu  = (const float*)d_in[9];
    const float* bmu  = (const float*)d_in[10];
    const float* Wlv  = (const float*)d_in[11];
    const float* blv  = (const float*)d_in[12];
    float* out = (float*)d_out;

    const int N = N_NODES, E = N_EDGES;
    const int* srcp = eidx;
    const int* dstp = eidx + E;

    // workspace layout
    ushort* w1h = (ushort*)d_ws;            // 4096
    ushort* w1l = w1h + 4096;               // 4096
    ushort* w2h = w1l + 4096;               // 16384
    ushort* w2l = w2h + 16384;              // 16384
    ushort* w3h = w2l + 16384;              // 16384
    ushort* w3l = w3h + 16384;              // 16384
    ushort* A   = w3l + 16384;              // N*128 bf16 (hws, gathered)
    float*  B   = (float*)(A + (size_t)N * 128);  // N*128 fp32 (h)
    float*  dis = B + (size_t)N * 128;      // N
    int*   hist = (int*)(dis + N);          // N
    int*   rp   = hist + N;                 // N+2
    int*   partials = rp + (N + 2);         // 128
    int*   bktCursor = partials + 128;      // 512
    int*   packed = bktCursor + 512;        // E
    int*   col    = packed + E;             // E

    const int gN = (N + 255) / 256;
    const int gE = (E + 255) / 256;
    const int nScanBlocks = (N + 1023) / 1024;

    // degree + rp
    k_zero_int<<<gN, 256, 0, stream>>>(hist, N);
    k_hist<<<gE, 256, 0, stream>>>(dstp, hist, E);
    k_dis<<<gN, 256, 0, stream>>>(hist, dis, N);
    k_scan1<<<nScanBlocks, 256, 0, stream>>>(hist, rp, partials, N);
    k_scan2<<<1, 128, 0, stream>>>(partials, nScanBlocks);
    k_scan3<<<gN, 256, 0, stream>>>(hist, rp, partials, N, E);

    // binned CSR build (col only)
    k_binit<<<2, 256, 0, stream>>>(rp, bktCursor);
    k_binA<<<(E + 4095) / 4096, 256, 0, stream>>>(srcp, dstp, bktCursor, packed, E);
    k_binB<<<NB, 256, 0, stream>>>(rp, packed, col, N);

    // W packs
    k_pack<<<16, 256, 0, stream>>>(W1, w1h, w1l, IN_DIM, 4096);
    k_pack<<<64, 256, 0, stream>>>(W2, w2h, w2l, HID, 16384);
    k_pack<<<64, 256, 0, stream>>>(W3, w3h, w3l, HID, 16384);

    const int gGemm = (N + 63) / 64;
    const int gAgg  = (N + 15) / 16;

    k_gemm_mfma<1, IN_DIM><<<gGemm, 256, 0, stream>>>(x, w1h, w1l, dis, A, N);
    k_agg<<<gAgg, 256, 0, stream>>>(A, rp, col, dis, b1, B, N);
    k_gemm_mfma<4, HID><<<gGemm, 256, 0, stream>>>(B, w2h, w2l, dis, A, N);
    k_agg<<<gAgg, 256, 0, stream>>>(A, rp, col, dis, b2, B, N);
    k_gemm_mfma<4, HID><<<gGemm, 256, 0, stream>>>(B, w3h, w3l, dis, A, N);
    k_agg<<<gAgg, 256, 0, stream>>>(A, rp, col, dis, b3, B, N);
    k_pool_head<<<N_GRAPHS, 256, 0, stream>>>(B, batch, Wmu, bmu, Wlv, blv, out, N);
}

// Round 6
// 649.482 us; speedup vs baseline: 2.9706x; 1.1696x over previous
//
#include <hip/hip_runtime.h>
#include <hip/hip_bf16.h>

#define N_NODES 100000
#define N_EDGES 3200000
#define N_GRAPHS 512
#define IN_DIM 29
#define HID 128
#define LAT 256
#define NB 391   // ceil(N_NODES/256) dst-buckets

typedef unsigned int uint;
typedef unsigned short ushort;
typedef float v4f __attribute__((ext_vector_type(4)));
typedef short v8s __attribute__((ext_vector_type(8)));

// round-to-nearest-even fp32 -> bf16 (finite inputs)
__device__ __forceinline__ ushort f2bf(float f) {
    uint u = __float_as_uint(f);
    return (ushort)((u + 0x7FFFu + ((u >> 16) & 1u)) >> 16);
}
__device__ __forceinline__ float bf2f(ushort h) { return __uint_as_float(((uint)h) << 16); }
__device__ __forceinline__ float bf_lo(uint p) { return __uint_as_float(p << 16); }
__device__ __forceinline__ float bf_hi(uint p) { return __uint_as_float(p & 0xFFFF0000u); }

__device__ __forceinline__ void bfadd(float* a, uint4 q) {
    a[0] += bf_lo(q.x); a[1] += bf_hi(q.x);
    a[2] += bf_lo(q.y); a[3] += bf_hi(q.y);
    a[4] += bf_lo(q.z); a[5] += bf_hi(q.z);
    a[6] += bf_lo(q.w); a[7] += bf_hi(q.w);
}

// ---------------- bucket-level histogram / scan ----------------

__global__ __launch_bounds__(256) void k_zero_small(int* p, int n) {
    int i = blockIdx.x * 256 + threadIdx.x;
    if (i < n) p[i] = 0;
}

__global__ __launch_bounds__(256) void k_bhist(const int* __restrict__ dst, int* __restrict__ bktCnt, int e) {
    __shared__ int h[NB];
    for (int i = threadIdx.x; i < NB; i += 256) h[i] = 0;
    __syncthreads();
    int idx = blockIdx.x * 4096 + threadIdx.x;
    #pragma unroll
    for (int t = 0; t < 16; ++t, idx += 256)
        if (idx < e) atomicAdd(&h[dst[idx] >> 8], 1);
    __syncthreads();
    for (int i = threadIdx.x; i < NB; i += 256) {
        int c = h[i];
        if (c) atomicAdd(&bktCnt[i], c);
    }
}

// single block: exclusive scan of bktCnt -> bktStart[NB+1], bktCursor
__global__ __launch_bounds__(512) void k_bscan(const int* __restrict__ bktCnt, int* __restrict__ bktStart,
                                               int* __restrict__ bktCursor, int e) {
    __shared__ int sh[512];
    int t = threadIdx.x;
    int v = (t < NB) ? bktCnt[t] : 0;
    sh[t] = v;
    __syncthreads();
    for (int off = 1; off < 512; off <<= 1) {
        int x = (t >= off) ? sh[t - off] : 0;
        __syncthreads();
        sh[t] += x;
        __syncthreads();
    }
    int excl = sh[t] - v;
    if (t < NB) { bktStart[t] = excl; bktCursor[t] = excl; }
    if (t == NB) bktStart[NB] = e;
}

// ---------------- two-phase binned CSR build ----------------

// Phase A: bin edges by dst>>8; pack (dst&255)<<17 | src
__global__ __launch_bounds__(256, 4) void k_binA(const int* __restrict__ src, const int* __restrict__ dst,
                                                 int* __restrict__ bktCursor, int* __restrict__ packed, int e) {
    __shared__ int hist[NB];
    __shared__ int base[NB];
    for (int i = threadIdx.x; i < NB; i += 256) hist[i] = 0;
    __syncthreads();
    int d[16], s[16];
    const int blockStart = blockIdx.x * 4096;
    #pragma unroll
    for (int t = 0; t < 16; ++t) {
        int idx = blockStart + t * 256 + threadIdx.x;
        if (idx < e) {
            d[t] = dst[idx];
            s[t] = src[idx];
            atomicAdd(&hist[d[t] >> 8], 1);
        } else d[t] = -1;
    }
    __syncthreads();
    for (int i = threadIdx.x; i < NB; i += 256) {
        int c = hist[i];
        base[i] = c ? atomicAdd(&bktCursor[i], c) : 0;
    }
    __syncthreads();
    #pragma unroll
    for (int t = 0; t < 16; ++t) {
        if (d[t] >= 0) {
            int b = d[t] >> 8;
            int pos = atomicAdd(&base[b], 1);
            packed[pos] = ((d[t] & 255) << 17) | s[t];
        }
    }
}

// Phase B: per bucket — count per-node degree in LDS, scan -> rp & dis (coalesced),
// then scatter col to final CSR positions (L2-resident region).
__global__ __launch_bounds__(256, 4) void k_binB(const int* __restrict__ bktStart, const int* __restrict__ packed,
                                                 int* __restrict__ col, int* __restrict__ rp,
                                                 float* __restrict__ dis, int n, int e) {
    const int b = blockIdx.x;
    const int segS = bktStart[b];
    const int segE = bktStart[b + 1];
    __shared__ int cnt[256];
    __shared__ int sh[256];
    __shared__ int cur[256];
    int t = threadIdx.x;
    cnt[t] = 0;
    __syncthreads();
    for (int j = segS + t; j < segE; j += 256) atomicAdd(&cnt[packed[j] >> 17], 1);
    __syncthreads();
    int v = cnt[t];
    sh[t] = v;
    __syncthreads();
    for (int off = 1; off < 256; off <<= 1) {
        int x = (t >= off) ? sh[t - off] : 0;
        __syncthreads();
        sh[t] += x;
        __syncthreads();
    }
    int excl = sh[t] - v;
    int node = (b << 8) + t;
    cur[t] = segS + excl;
    if (node < n) {
        rp[node] = segS + excl;
        dis[node] = rsqrtf((float)v + 1.0f);
    }
    if (node == n) rp[n] = e;
    __syncthreads();
    for (int j = segS + t; j < segE; j += 256) {
        int pk = packed[j];
        int dl = pk >> 17;
        int pos = atomicAdd(&cur[dl], 1);
        col[pos] = pk & 0x1FFFF;
    }
}

// ---------------- W pack (all 3 layers): fp32 -> hi/lo bf16 planes in B-fragment order ----------------
// layout index = ((kstep*8 + ntile)*64 + lane)*8 + j
// element = W[kstep*32 + (lane>>4)*8 + j][ntile*16 + (lane&15)]

__device__ __forceinline__ void pack_one(const float* W, ushort* hi, ushort* lo, int Ksrc, int idx) {
    int j = idx & 7;
    int lane = (idx >> 3) & 63;
    int nt = (idx >> 9) & 7;
    int ks = idx >> 12;
    int k = ks * 32 + (lane >> 4) * 8 + j;
    int n = nt * 16 + (lane & 15);
    float v = (k < Ksrc) ? W[k * 128 + n] : 0.f;
    ushort h = f2bf(v);
    ushort l = f2bf(v - bf2f(h));
    hi[idx] = h;
    lo[idx] = l;
}

__global__ __launch_bounds__(256) void k_pack_all(const float* __restrict__ W1, const float* __restrict__ W2,
                                                  const float* __restrict__ W3,
                                                  ushort* w1h, ushort* w1l, ushort* w2h, ushort* w2l,
                                                  ushort* w3h, ushort* w3l) {
    int idx = blockIdx.x * 256 + threadIdx.x;
    if (idx < 4096) {
        pack_one(W1, w1h, w1l, IN_DIM, idx);
    } else if (idx < 4096 + 16384) {
        pack_one(W2, w2h, w2l, HID, idx - 4096);
    } else if (idx < 4096 + 32768) {
        pack_one(W3, w3h, w3l, HID, idx - 4096 - 16384);
    }
}

// ---------------- MFMA GEMM: hws_bf16[n][128] = dis[n] * (in_f32[n][KSRC] @ W) ----------------
// Split precision: acc = Ahi@Whi + Ahi@Wlo + Alo@Whi.

template <int KSTEPS, int KSRC>
__global__ __launch_bounds__(256, 4) void k_gemm_mfma(const float* __restrict__ in,
                                                      const ushort* __restrict__ Whi,
                                                      const ushort* __restrict__ Wlo,
                                                      const float* __restrict__ dis,
                                                      ushort* __restrict__ out, int n) {
    const int wave = threadIdx.x >> 6;
    const int lane = threadIdx.x & 63;
    const int m0 = (blockIdx.x * 4 + wave) * 16;
    if (m0 >= n) return;
    int row = m0 + (lane & 15);
    if (row >= n) row = n - 1;
    const int kh = (lane >> 4) * 8;
    const float* rptr = in + (size_t)row * KSRC + kh;

    v4f acc[8];
    #pragma unroll
    for (int t = 0; t < 8; ++t) acc[t] = (v4f){0.f, 0.f, 0.f, 0.f};

    #pragma unroll
    for (int ks = 0; ks < KSTEPS; ++ks) {
        float a[8];
        if constexpr (KSRC == IN_DIM) {
            #pragma unroll
            for (int j = 0; j < 8; ++j) a[j] = (kh + j < KSRC) ? rptr[j] : 0.f;
        } else {
            float4 p0 = *(const float4*)(rptr + ks * 32);
            float4 p1 = *(const float4*)(rptr + ks * 32 + 4);
            a[0] = p0.x; a[1] = p0.y; a[2] = p0.z; a[3] = p0.w;
            a[4] = p1.x; a[5] = p1.y; a[6] = p1.z; a[7] = p1.w;
        }
        v8s ahi, alo;
        #pragma unroll
        for (int j = 0; j < 8; ++j) {
            ushort h = f2bf(a[j]);
            ushort l = f2bf(a[j] - bf2f(h));
            ahi[j] = (short)h;
            alo[j] = (short)l;
        }
        const ushort* bh = Whi + (size_t)(ks * 8) * 512 + (size_t)lane * 8;
        const ushort* bl = Wlo + (size_t)(ks * 8) * 512 + (size_t)lane * 8;
        #pragma unroll
        for (int nt = 0; nt < 8; ++nt) {
            v8s bhi = *(const v8s*)(bh + nt * 512);
            v8s blo = *(const v8s*)(bl + nt * 512);
            acc[nt] = __builtin_amdgcn_mfma_f32_16x16x32_bf16(ahi, bhi, acc[nt], 0, 0, 0);
            acc[nt] = __builtin_amdgcn_mfma_f32_16x16x32_bf16(ahi, blo, acc[nt], 0, 0, 0);
            acc[nt] = __builtin_amdgcn_mfma_f32_16x16x32_bf16(alo, bhi, acc[nt], 0, 0, 0);
        }
    }

    // C/D layout: col = lane&15, row = (lane>>4)*4 + reg ; scale by dis[row]
    const int orow0 = m0 + (lane >> 4) * 4;
    const int col0 = lane & 15;
    #pragma unroll
    for (int r = 0; r < 4; ++r) {
        int orow = orow0 + r;
        if (orow < n) {
            float dv = dis[orow];
            #pragma unroll
            for (int nt = 0; nt < 8; ++nt)
                out[(size_t)orow * 128 + nt * 16 + col0] = f2bf(acc[nt][r] * dv);
        }
    }
}

// ---------------- aggregation: 16 lanes/node, 8 ch/lane, unweighted gather-sum ----------------
// out[i][:] = relu( dis[i] * ( sum_j hws[col[j]][:] + hws[i][:] ) + b[:] )

__global__ __launch_bounds__(256, 8) void k_agg(const ushort* __restrict__ hws, const int* __restrict__ rp,
                                                const int* __restrict__ col, const float* __restrict__ dis,
                                                const float* __restrict__ bias, float* __restrict__ out, int n) {
    int node = (int)((blockIdx.x * 256 + threadIdx.x) >> 4);
    if (node >= n) return;
    int c8 = (threadIdx.x & 15) << 3;
    int s = rp[node], e = rp[node + 1];
    float A[8] = {0.f, 0.f, 0.f, 0.f, 0.f, 0.f, 0.f, 0.f};
    float B[8] = {0.f, 0.f, 0.f, 0.f, 0.f, 0.f, 0.f, 0.f};
    int j = s;
    for (; j + 3 < e; j += 4) {
        int c0 = col[j], c1 = col[j + 1], c2 = col[j + 2], c3 = col[j + 3];
        uint4 q0 = *(const uint4*)(hws + ((size_t)c0 << 7) + c8);
        uint4 q1 = *(const uint4*)(hws + ((size_t)c1 << 7) + c8);
        uint4 q2 = *(const uint4*)(hws + ((size_t)c2 << 7) + c8);
        uint4 q3 = *(const uint4*)(hws + ((size_t)c3 << 7) + c8);
        bfadd(A, q0); bfadd(B, q1); bfadd(A, q2); bfadd(B, q3);
    }
    for (; j < e; ++j) {
        int c = col[j];
        uint4 q = *(const uint4*)(hws + ((size_t)c << 7) + c8);
        bfadd(A, q);
    }
    uint4 qs = *(const uint4*)(hws + ((size_t)node << 7) + c8);
    bfadd(A, qs);
    float dv = dis[node];
    float4 bv0 = *(const float4*)(bias + c8);
    float4 bv1 = *(const float4*)(bias + c8 + 4);
    float4 r0, r1;
    r0.x = fmaxf(dv * (A[0] + B[0]) + bv0.x, 0.f);
    r0.y = fmaxf(dv * (A[1] + B[1]) + bv0.y, 0.f);
    r0.z = fmaxf(dv * (A[2] + B[2]) + bv0.z, 0.f);
    r0.w = fmaxf(dv * (A[3] + B[3]) + bv0.w, 0.f);
    r1.x = fmaxf(dv * (A[4] + B[4]) + bv1.x, 0.f);
    r1.y = fmaxf(dv * (A[5] + B[5]) + bv1.y, 0.f);
    r1.z = fmaxf(dv * (A[6] + B[6]) + bv1.z, 0.f);
    r1.w = fmaxf(dv * (A[7] + B[7]) + bv1.w, 0.f);
    *(float4*)(out + (size_t)node * 128 + c8) = r0;
    *(float4*)(out + (size_t)node * 128 + c8 + 4) = r1;
}

// ---------------- fused mean-pool + heads ----------------

__global__ __launch_bounds__(256) void k_pool_head(const float* __restrict__ h, const int* __restrict__ batch,
                                                   const float* __restrict__ Wmu, const float* __restrict__ bmu,
                                                   const float* __restrict__ Wlv, const float* __restrict__ blv,
                                                   float* __restrict__ out, int n) {
    int g = blockIdx.x;
    int t = threadIdx.x;
    int lo = 0, hi = n;
    while (lo < hi) { int m = (lo + hi) >> 1; if (batch[m] < g) lo = m + 1; else hi = m; }
    int start = lo;
    hi = n;
    while (lo < hi) { int m = (lo + hi) >> 1; if (batch[m] < g + 1) lo = m + 1; else hi = m; }
    int end = lo;

    __shared__ float sh[256];
    __shared__ float pooled[128];
    int c = t & 127, half = t >> 7;
    float acc = 0.f;
    for (int i = start + half; i < end; i += 2) acc += h[(size_t)i * 128 + c];
    sh[t] = acc;
    __syncthreads();
    if (t < 128) {
        float cnt = (float)(end - start);
        float inv = 1.0f / fmaxf(cnt, 1.0f);
        pooled[t] = (sh[t] + sh[t + 128]) * inv;
    }
    __syncthreads();
    float amu = bmu[t], alv = blv[t];
    for (int k = 0; k < 128; k += 4) {
        float p0 = pooled[k], p1 = pooled[k + 1], p2 = pooled[k + 2], p3 = pooled[k + 3];
        amu += p0 * Wmu[(k + 0) * 256 + t] + p1 * Wmu[(k + 1) * 256 + t]
             + p2 * Wmu[(k + 2) * 256 + t] + p3 * Wmu[(k + 3) * 256 + t];
        alv += p0 * Wlv[(k + 0) * 256 + t] + p1 * Wlv[(k + 1) * 256 + t]
             + p2 * Wlv[(k + 2) * 256 + t] + p3 * Wlv[(k + 3) * 256 + t];
    }
    out[(size_t)g * 256 + t] = amu;
    out[(size_t)N_GRAPHS * 256 + (size_t)g * 256 + t] = alv;
}

// ---------------- launch ----------------

extern "C" void kernel_launch(void* const* d_in, const int* in_sizes, int n_in,
                              void* d_out, int out_size, void* d_ws, size_t ws_size,
                              hipStream_t stream) {
    const float* x    = (const float*)d_in[0];
    const int*   eidx = (const int*)d_in[1];
    const int*   batch= (const int*)d_in[2];
    const float* W1   = (const float*)d_in[3];
    const float* b1   = (const float*)d_in[4];
    const float* W2   = (const float*)d_in[5];
    const float* b2   = (const float*)d_in[6];
    const float* W3   = (const float*)d_in[7];
    const float* b3   = (const float*)d_in[8];
    const float* Wmu  = (const float*)d_in[9];
    const float* bmu  = (const float*)d_in[10];
    const float* Wlv  = (const float*)d_in[11];
    const float* blv  = (const float*)d_in[12];
    float* out = (float*)d_out;

    const int N = N_NODES, E = N_EDGES;
    const int* srcp = eidx;
    const int* dstp = eidx + E;

    // workspace layout
    ushort* w1h = (ushort*)d_ws;            // 4096
    ushort* w1l = w1h + 4096;               // 4096
    ushort* w2h = w1l + 4096;               // 16384
    ushort* w2l = w2h + 16384;              // 16384
    ushort* w3h = w2l + 16384;              // 16384
    ushort* w3l = w3h + 16384;              // 16384
    ushort* A   = w3l + 16384;              // N*128 bf16 (hws, gathered)
    float*  B   = (float*)(A + (size_t)N * 128);  // N*128 fp32 (h)
    float*  dis = B + (size_t)N * 128;      // N
    int*   rp   = (int*)(dis + N);          // N+2
    int*   bktCnt    = rp + (N + 2);        // NB (pad 512)
    int*   bktStart  = bktCnt + 512;        // NB+1 (pad 512)
    int*   bktCursor = bktStart + 512;      // NB (pad 512)
    int*   packed = bktCursor + 512;        // E
    int*   col    = packed + E;             // E

    const int gE4096 = (E + 4095) / 4096;   // 782

    // bucket-level CSR build (no 100k-bin global atomics)
    k_zero_small<<<2, 256, 0, stream>>>(bktCnt, NB);
    k_bhist<<<gE4096, 256, 0, stream>>>(dstp, bktCnt, E);
    k_bscan<<<1, 512, 0, stream>>>(bktCnt, bktStart, bktCursor, E);
    k_binA<<<gE4096, 256, 0, stream>>>(srcp, dstp, bktCursor, packed, E);
    k_binB<<<NB, 256, 0, stream>>>(bktStart, packed, col, rp, dis, N, E);

    // W packs (one launch)
    k_pack_all<<<144, 256, 0, stream>>>(W1, W2, W3, w1h, w1l, w2h, w2l, w3h, w3l);

    const int gGemm = (N + 63) / 64;
    const int gAgg  = (N + 15) / 16;

    k_gemm_mfma<1, IN_DIM><<<gGemm, 256, 0, stream>>>(x, w1h, w1l, dis, A, N);
    k_agg<<<gAgg, 256, 0, stream>>>(A, rp, col, dis, b1, B, N);
    k_gemm_mfma<4, HID><<<gGemm, 256, 0, stream>>>(B, w2h, w2l, dis, A, N);
    k_agg<<<gAgg, 256, 0, stream>>>(A, rp, col, dis, b2, B, N);
    k_gemm_mfma<4, HID><<<gGemm, 256, 0, stream>>>(B, w3h, w3l, dis, A, N);
    k_agg<<<gAgg, 256, 0, stream>>>(A, rp, col, dis, b3, B, N);
    k_pool_head<<<N_GRAPHS, 256, 0, stream>>>(B, batch, Wmu, bmu, Wlv, blv, out, N);
}

// Round 7
// 619.602 us; speedup vs baseline: 3.1138x; 1.0482x over previous
//
#include <hip/hip_runtime.h>
#include <hip/hip_bf16.h>

#define N_NODES 100000
#define N_EDGES 3200000
#define N_GRAPHS 512
#define IN_DIM 29
#define HID 128
#define LAT 256
#define NB 391   // ceil(N_NODES/256) dst-buckets

typedef unsigned int uint;
typedef unsigned short ushort;
typedef float v4f __attribute__((ext_vector_type(4)));
typedef short v8s __attribute__((ext_vector_type(8)));

// round-to-nearest-even fp32 -> bf16 (finite inputs)
__device__ __forceinline__ ushort f2bf(float f) {
    uint u = __float_as_uint(f);
    return (ushort)((u + 0x7FFFu + ((u >> 16) & 1u)) >> 16);
}
__device__ __forceinline__ float bf2f(ushort h) { return __uint_as_float(((uint)h) << 16); }
__device__ __forceinline__ float bf_lo(uint p) { return __uint_as_float(p << 16); }
__device__ __forceinline__ float bf_hi(uint p) { return __uint_as_float(p & 0xFFFF0000u); }
__device__ __forceinline__ uint pack2(float a, float b) {
    return (uint)f2bf(a) | ((uint)f2bf(b) << 16);
}

__device__ __forceinline__ void bfadd(float* a, uint4 q) {
    a[0] += bf_lo(q.x); a[1] += bf_hi(q.x);
    a[2] += bf_lo(q.y); a[3] += bf_hi(q.y);
    a[4] += bf_lo(q.z); a[5] += bf_hi(q.z);
    a[6] += bf_lo(q.w); a[7] += bf_hi(q.w);
}

// ---------------- bucket-level histogram / scan ----------------

__global__ __launch_bounds__(256) void k_zero_small(int* p, int n) {
    int i = blockIdx.x * 256 + threadIdx.x;
    if (i < n) p[i] = 0;
}

__global__ __launch_bounds__(256) void k_bhist(const int* __restrict__ dst, int* __restrict__ bktCnt, int e) {
    __shared__ int h[NB];
    for (int i = threadIdx.x; i < NB; i += 256) h[i] = 0;
    __syncthreads();
    int idx = blockIdx.x * 4096 + threadIdx.x;
    #pragma unroll
    for (int t = 0; t < 16; ++t, idx += 256)
        if (idx < e) atomicAdd(&h[dst[idx] >> 8], 1);
    __syncthreads();
    for (int i = threadIdx.x; i < NB; i += 256) {
        int c = h[i];
        if (c) atomicAdd(&bktCnt[i], c);
    }
}

// single block: exclusive scan of bktCnt -> bktStart[NB+1], bktCursor
__global__ __launch_bounds__(512) void k_bscan(const int* __restrict__ bktCnt, int* __restrict__ bktStart,
                                               int* __restrict__ bktCursor, int e) {
    __shared__ int sh[512];
    int t = threadIdx.x;
    int v = (t < NB) ? bktCnt[t] : 0;
    sh[t] = v;
    __syncthreads();
    for (int off = 1; off < 512; off <<= 1) {
        int x = (t >= off) ? sh[t - off] : 0;
        __syncthreads();
        sh[t] += x;
        __syncthreads();
    }
    int excl = sh[t] - v;
    if (t < NB) { bktStart[t] = excl; bktCursor[t] = excl; }
    if (t == NB) bktStart[NB] = e;
}

// ---------------- two-phase binned CSR build ----------------

// Phase A: bin edges by dst>>8; pack (dst&255)<<17 | src
__global__ __launch_bounds__(256, 4) void k_binA(const int* __restrict__ src, const int* __restrict__ dst,
                                                 int* __restrict__ bktCursor, int* __restrict__ packed, int e) {
    __shared__ int hist[NB];
    __shared__ int base[NB];
    for (int i = threadIdx.x; i < NB; i += 256) hist[i] = 0;
    __syncthreads();
    int d[16], s[16];
    const int blockStart = blockIdx.x * 4096;
    #pragma unroll
    for (int t = 0; t < 16; ++t) {
        int idx = blockStart + t * 256 + threadIdx.x;
        if (idx < e) {
            d[t] = dst[idx];
            s[t] = src[idx];
            atomicAdd(&hist[d[t] >> 8], 1);
        } else d[t] = -1;
    }
    __syncthreads();
    for (int i = threadIdx.x; i < NB; i += 256) {
        int c = hist[i];
        base[i] = c ? atomicAdd(&bktCursor[i], c) : 0;
    }
    __syncthreads();
    #pragma unroll
    for (int t = 0; t < 16; ++t) {
        if (d[t] >= 0) {
            int b = d[t] >> 8;
            int pos = atomicAdd(&base[b], 1);
            packed[pos] = ((d[t] & 255) << 17) | s[t];
        }
    }
}

// Phase B: per bucket — count per-node degree in LDS, scan -> rp & dis (coalesced),
// then scatter col to final CSR positions (L2-resident region).
__global__ __launch_bounds__(256, 4) void k_binB(const int* __restrict__ bktStart, const int* __restrict__ packed,
                                                 int* __restrict__ col, int* __restrict__ rp,
                                                 float* __restrict__ dis, int n, int e) {
    const int b = blockIdx.x;
    const int segS = bktStart[b];
    const int segE = bktStart[b + 1];
    __shared__ int cnt[256];
    __shared__ int sh[256];
    __shared__ int cur[256];
    int t = threadIdx.x;
    cnt[t] = 0;
    __syncthreads();
    for (int j = segS + t; j < segE; j += 256) atomicAdd(&cnt[packed[j] >> 17], 1);
    __syncthreads();
    int v = cnt[t];
    sh[t] = v;
    __syncthreads();
    for (int off = 1; off < 256; off <<= 1) {
        int x = (t >= off) ? sh[t - off] : 0;
        __syncthreads();
        sh[t] += x;
        __syncthreads();
    }
    int excl = sh[t] - v;
    int node = (b << 8) + t;
    cur[t] = segS + excl;
    if (node < n) {
        rp[node] = segS + excl;
        dis[node] = rsqrtf((float)v + 1.0f);
    }
    if (node == n) rp[n] = e;
    __syncthreads();
    for (int j = segS + t; j < segE; j += 256) {
        int pk = packed[j];
        int dl = pk >> 17;
        int pos = atomicAdd(&cur[dl], 1);
        col[pos] = pk & 0x1FFFF;
    }
}

// ---------------- W pack (all 3 layers): fp32 -> hi/lo bf16 planes in B-fragment order ----------------
// layout index = ((kstep*8 + ntile)*64 + lane)*8 + j
// element = W[kstep*32 + (lane>>4)*8 + j][ntile*16 + (lane&15)]

__device__ __forceinline__ void pack_one(const float* W, ushort* hi, ushort* lo, int Ksrc, int idx) {
    int j = idx & 7;
    int lane = (idx >> 3) & 63;
    int nt = (idx >> 9) & 7;
    int ks = idx >> 12;
    int k = ks * 32 + (lane >> 4) * 8 + j;
    int n = nt * 16 + (lane & 15);
    float v = (k < Ksrc) ? W[k * 128 + n] : 0.f;
    ushort h = f2bf(v);
    ushort l = f2bf(v - bf2f(h));
    hi[idx] = h;
    lo[idx] = l;
}

__global__ __launch_bounds__(256) void k_pack_all(const float* __restrict__ W1, const float* __restrict__ W2,
                                                  const float* __restrict__ W3,
                                                  ushort* w1h, ushort* w1l, ushort* w2h, ushort* w2l,
                                                  ushort* w3h, ushort* w3l) {
    int idx = blockIdx.x * 256 + threadIdx.x;
    if (idx < 4096) {
        pack_one(W1, w1h, w1l, IN_DIM, idx);
    } else if (idx < 4096 + 16384) {
        pack_one(W2, w2h, w2l, HID, idx - 4096);
    } else if (idx < 4096 + 32768) {
        pack_one(W3, w3h, w3l, HID, idx - 4096 - 16384);
    }
}

// ---------------- MFMA GEMM (layer 1): hws_bf16[n][128] = dis[n] * (x_f32[n][29] @ W) ----------------
// Split precision: acc = Ahi@Whi + Ahi@Wlo + Alo@Whi.

__global__ __launch_bounds__(256, 4) void k_gemm_mfma_f32(const float* __restrict__ in,
                                                          const ushort* __restrict__ Whi,
                                                          const ushort* __restrict__ Wlo,
                                                          const float* __restrict__ dis,
                                                          ushort* __restrict__ out, int n) {
    const int wave = threadIdx.x >> 6;
    const int lane = threadIdx.x & 63;
    const int m0 = (blockIdx.x * 4 + wave) * 16;
    if (m0 >= n) return;
    int row = m0 + (lane & 15);
    if (row >= n) row = n - 1;
    const int kh = (lane >> 4) * 8;
    const float* rptr = in + (size_t)row * IN_DIM + kh;

    v4f acc[8];
    #pragma unroll
    for (int t = 0; t < 8; ++t) acc[t] = (v4f){0.f, 0.f, 0.f, 0.f};

    float a[8];
    #pragma unroll
    for (int j = 0; j < 8; ++j) a[j] = (kh + j < IN_DIM) ? rptr[j] : 0.f;
    v8s ahi, alo;
    #pragma unroll
    for (int j = 0; j < 8; ++j) {
        ushort h = f2bf(a[j]);
        ushort l = f2bf(a[j] - bf2f(h));
        ahi[j] = (short)h;
        alo[j] = (short)l;
    }
    const ushort* bh = Whi + (size_t)lane * 8;
    const ushort* bl = Wlo + (size_t)lane * 8;
    #pragma unroll
    for (int nt = 0; nt < 8; ++nt) {
        v8s bhi = *(const v8s*)(bh + nt * 512);
        v8s blo = *(const v8s*)(bl + nt * 512);
        acc[nt] = __builtin_amdgcn_mfma_f32_16x16x32_bf16(ahi, bhi, acc[nt], 0, 0, 0);
        acc[nt] = __builtin_amdgcn_mfma_f32_16x16x32_bf16(ahi, blo, acc[nt], 0, 0, 0);
        acc[nt] = __builtin_amdgcn_mfma_f32_16x16x32_bf16(alo, bhi, acc[nt], 0, 0, 0);
    }

    const int orow0 = m0 + (lane >> 4) * 4;
    const int col0 = lane & 15;
    #pragma unroll
    for (int r = 0; r < 4; ++r) {
        int orow = orow0 + r;
        if (orow < n) {
            float dv = dis[orow];
            #pragma unroll
            for (int nt = 0; nt < 8; ++nt)
                out[(size_t)orow * 128 + nt * 16 + col0] = f2bf(acc[nt][r] * dv);
        }
    }
}

// ---------------- MFMA GEMM (layers 2,3): hws_bf16[n][128] = dis[n] * (h_bf16[n][128] @ W) ----------------
// A is exact bf16 -> Alo = 0 -> only 2 MFMAs: A@Whi + A@Wlo.

__global__ __launch_bounds__(256, 4) void k_gemm_mfma_bf(const ushort* __restrict__ in,
                                                         const ushort* __restrict__ Whi,
                                                         const ushort* __restrict__ Wlo,
                                                         const float* __restrict__ dis,
                                                         ushort* __restrict__ out, int n) {
    const int wave = threadIdx.x >> 6;
    const int lane = threadIdx.x & 63;
    const int m0 = (blockIdx.x * 4 + wave) * 16;
    if (m0 >= n) return;
    int row = m0 + (lane & 15);
    if (row >= n) row = n - 1;
    const int kh = (lane >> 4) * 8;
    const ushort* rptr = in + (size_t)row * 128 + kh;

    v4f acc[8];
    #pragma unroll
    for (int t = 0; t < 8; ++t) acc[t] = (v4f){0.f, 0.f, 0.f, 0.f};

    #pragma unroll
    for (int ks = 0; ks < 4; ++ks) {
        v8s a = *(const v8s*)(rptr + ks * 32);
        const ushort* bh = Whi + (size_t)(ks * 8) * 512 + (size_t)lane * 8;
        const ushort* bl = Wlo + (size_t)(ks * 8) * 512 + (size_t)lane * 8;
        #pragma unroll
        for (int nt = 0; nt < 8; ++nt) {
            v8s bhi = *(const v8s*)(bh + nt * 512);
            v8s blo = *(const v8s*)(bl + nt * 512);
            acc[nt] = __builtin_amdgcn_mfma_f32_16x16x32_bf16(a, bhi, acc[nt], 0, 0, 0);
            acc[nt] = __builtin_amdgcn_mfma_f32_16x16x32_bf16(a, blo, acc[nt], 0, 0, 0);
        }
    }

    const int orow0 = m0 + (lane >> 4) * 4;
    const int col0 = lane & 15;
    #pragma unroll
    for (int r = 0; r < 4; ++r) {
        int orow = orow0 + r;
        if (orow < n) {
            float dv = dis[orow];
            #pragma unroll
            for (int nt = 0; nt < 8; ++nt)
                out[(size_t)orow * 128 + nt * 16 + col0] = f2bf(acc[nt][r] * dv);
        }
    }
}

// ---------------- aggregation: 16 lanes/node, 8 ch/lane, unweighted gather-sum ----------------
// out[i][:] = bf16( relu( dis[i] * ( sum_j hws[col[j]][:] + hws[i][:] ) + b[:] ) )

__global__ __launch_bounds__(256, 8) void k_agg(const ushort* __restrict__ hws, const int* __restrict__ rp,
                                                const int* __restrict__ col, const float* __restrict__ dis,
                                                const float* __restrict__ bias, ushort* __restrict__ out, int n) {
    int node = (int)((blockIdx.x * 256 + threadIdx.x) >> 4);
    if (node >= n) return;
    int c8 = (threadIdx.x & 15) << 3;
    int s = rp[node], e = rp[node + 1];
    float A[8] = {0.f, 0.f, 0.f, 0.f, 0.f, 0.f, 0.f, 0.f};
    float B[8] = {0.f, 0.f, 0.f, 0.f, 0.f, 0.f, 0.f, 0.f};
    int j = s;
    for (; j + 3 < e; j += 4) {
        int c0 = col[j], c1 = col[j + 1], c2 = col[j + 2], c3 = col[j + 3];
        uint4 q0 = *(const uint4*)(hws + ((size_t)c0 << 7) + c8);
        uint4 q1 = *(const uint4*)(hws + ((size_t)c1 << 7) + c8);
        uint4 q2 = *(const uint4*)(hws + ((size_t)c2 << 7) + c8);
        uint4 q3 = *(const uint4*)(hws + ((size_t)c3 << 7) + c8);
        bfadd(A, q0); bfadd(B, q1); bfadd(A, q2); bfadd(B, q3);
    }
    for (; j < e; ++j) {
        int c = col[j];
        uint4 q = *(const uint4*)(hws + ((size_t)c << 7) + c8);
        bfadd(A, q);
    }
    uint4 qs = *(const uint4*)(hws + ((size_t)node << 7) + c8);
    bfadd(A, qs);
    float dv = dis[node];
    float4 bv0 = *(const float4*)(bias + c8);
    float4 bv1 = *(const float4*)(bias + c8 + 4);
    float r0 = fmaxf(dv * (A[0] + B[0]) + bv0.x, 0.f);
    float r1 = fmaxf(dv * (A[1] + B[1]) + bv0.y, 0.f);
    float r2 = fmaxf(dv * (A[2] + B[2]) + bv0.z, 0.f);
    float r3 = fmaxf(dv * (A[3] + B[3]) + bv0.w, 0.f);
    float r4 = fmaxf(dv * (A[4] + B[4]) + bv1.x, 0.f);
    float r5 = fmaxf(dv * (A[5] + B[5]) + bv1.y, 0.f);
    float r6 = fmaxf(dv * (A[6] + B[6]) + bv1.z, 0.f);
    float r7 = fmaxf(dv * (A[7] + B[7]) + bv1.w, 0.f);
    uint4 o;
    o.x = pack2(r0, r1);
    o.y = pack2(r2, r3);
    o.z = pack2(r4, r5);
    o.w = pack2(r6, r7);
    *(uint4*)(out + (size_t)node * 128 + c8) = o;
}

// ---------------- fused mean-pool + heads (bf16 h input) ----------------

__global__ __launch_bounds__(256) void k_pool_head(const ushort* __restrict__ h, const int* __restrict__ batch,
                                                   const float* __restrict__ Wmu, const float* __restrict__ bmu,
                                                   const float* __restrict__ Wlv, const float* __restrict__ blv,
                                                   float* __restrict__ out, int n) {
    int g = blockIdx.x;
    int t = threadIdx.x;
    int lo = 0, hi = n;
    while (lo < hi) { int m = (lo + hi) >> 1; if (batch[m] < g) lo = m + 1; else hi = m; }
    int start = lo;
    hi = n;
    while (lo < hi) { int m = (lo + hi) >> 1; if (batch[m] < g + 1) lo = m + 1; else hi = m; }
    int end = lo;

    __shared__ float sh0[256];
    __shared__ float sh1[256];
    __shared__ float pooled[128];
    int lane = t & 63;       // channel pair index: channels lane*2, lane*2+1
    int grp = t >> 6;        // 0..3
    float a0 = 0.f, a1 = 0.f;
    for (int i = start + grp; i < end; i += 4) {
        uint q = *(const uint*)(h + (size_t)i * 128 + lane * 2);
        a0 += bf_lo(q);
        a1 += bf_hi(q);
    }
    sh0[t] = a0;
    sh1[t] = a1;
    __syncthreads();
    if (t < 64) {
        float cnt = (float)(end - start);
        float inv = 1.0f / fmaxf(cnt, 1.0f);
        float s0 = sh0[t] + sh0[t + 64] + sh0[t + 128] + sh0[t + 192];
        float s1 = sh1[t] + sh1[t + 64] + sh1[t + 128] + sh1[t + 192];
        pooled[t * 2] = s0 * inv;
        pooled[t * 2 + 1] = s1 * inv;
    }
    __syncthreads();
    float amu = bmu[t], alv = blv[t];
    for (int k = 0; k < 128; k += 4) {
        float p0 = pooled[k], p1 = pooled[k + 1], p2 = pooled[k + 2], p3 = pooled[k + 3];
        amu += p0 * Wmu[(k + 0) * 256 + t] + p1 * Wmu[(k + 1) * 256 + t]
             + p2 * Wmu[(k + 2) * 256 + t] + p3 * Wmu[(k + 3) * 256 + t];
        alv += p0 * Wlv[(k + 0) * 256 + t] + p1 * Wlv[(k + 1) * 256 + t]
             + p2 * Wlv[(k + 2) * 256 + t] + p3 * Wlv[(k + 3) * 256 + t];
    }
    out[(size_t)g * 256 + t] = amu;
    out[(size_t)N_GRAPHS * 256 + (size_t)g * 256 + t] = alv;
}

// ---------------- launch ----------------

extern "C" void kernel_launch(void* const* d_in, const int* in_sizes, int n_in,
                              void* d_out, int out_size, void* d_ws, size_t ws_size,
                              hipStream_t stream) {
    const float* x    = (const float*)d_in[0];
    const int*   eidx = (const int*)d_in[1];
    const int*   batch= (const int*)d_in[2];
    const float* W1   = (const float*)d_in[3];
    const float* b1   = (const float*)d_in[4];
    const float* W2   = (const float*)d_in[5];
    const float* b2   = (const float*)d_in[6];
    const float* W3   = (const float*)d_in[7];
    const float* b3   = (const float*)d_in[8];
    const float* Wmu  = (const float*)d_in[9];
    const float* bmu  = (const float*)d_in[10];
    const float* Wlv  = (const float*)d_in[11];
    const float* blv  = (const float*)d_in[12];
    float* out = (float*)d_out;

    const int N = N_NODES, E = N_EDGES;
    const int* srcp = eidx;
    const int* dstp = eidx + E;

    // workspace layout
    ushort* w1h = (ushort*)d_ws;            // 4096
    ushort* w1l = w1h + 4096;               // 4096
    ushort* w2h = w1l + 4096;               // 16384
    ushort* w2l = w2h + 16384;              // 16384
    ushort* w3h = w2l + 16384;              // 16384
    ushort* w3l = w3h + 16384;              // 16384
    ushort* A   = w3l + 16384;              // N*128 bf16 (hws, gathered)
    ushort* B   = A + (size_t)N * 128;      // N*128 bf16 (h)
    float*  dis = (float*)(B + (size_t)N * 128);  // N
    int*   rp   = (int*)(dis + N);          // N+2
    int*   bktCnt    = rp + (N + 2);        // NB (pad 512)
    int*   bktStart  = bktCnt + 512;        // NB+1 (pad 512)
    int*   bktCursor = bktStart + 512;      // NB (pad 512)
    int*   packed = bktCursor + 512;        // E
    int*   col    = packed + E;             // E

    const int gE4096 = (E + 4095) / 4096;   // 782

    // bucket-level CSR build
    k_zero_small<<<2, 256, 0, stream>>>(bktCnt, NB);
    k_bhist<<<gE4096, 256, 0, stream>>>(dstp, bktCnt, E);
    k_bscan<<<1, 512, 0, stream>>>(bktCnt, bktStart, bktCursor, E);
    k_binA<<<gE4096, 256, 0, stream>>>(srcp, dstp, bktCursor, packed, E);
    k_binB<<<NB, 256, 0, stream>>>(bktStart, packed, col, rp, dis, N, E);

    // W packs (one launch)
    k_pack_all<<<144, 256, 0, stream>>>(W1, W2, W3, w1h, w1l, w2h, w2l, w3h, w3l);

    const int gGemm = (N + 63) / 64;
    const int gAgg  = (N + 15) / 16;

    k_gemm_mfma_f32<<<gGemm, 256, 0, stream>>>(x, w1h, w1l, dis, A, N);
    k_agg<<<gAgg, 256, 0, stream>>>(A, rp, col, dis, b1, B, N);
    k_gemm_mfma_bf<<<gGemm, 256, 0, stream>>>(B, w2h, w2l, dis, A, N);
    k_agg<<<gAgg, 256, 0, stream>>>(A, rp, col, dis, b2, B, N);
    k_gemm_mfma_bf<<<gGemm, 256, 0, stream>>>(B, w3h, w3l, dis, A, N);
    k_agg<<<gAgg, 256, 0, stream>>>(A, rp, col, dis, b3, B, N);
    k_pool_head<<<N_GRAPHS, 256, 0, stream>>>(B, batch, Wmu, bmu, Wlv, blv, out, N);
}